// Round 9
// baseline (607.813 us; speedup 1.0000x reference)
//
#include <hip/hip_runtime.h>

typedef __attribute__((ext_vector_type(4))) float f32x4;
typedef __attribute__((ext_vector_type(8))) short short8;
typedef unsigned short u16;
typedef unsigned int u32;

__device__ __forceinline__ u16 f2bf(float f){
  u32 x = __float_as_uint(f);
  u32 r = x + 0x7fffu + ((x >> 16) & 1u);
  return (u16)(r >> 16);
}
__device__ __forceinline__ float bf2f32(u32 u){ return __uint_as_float(u << 16); }

__device__ __forceinline__ void gld_lds16(const u16* g, u16* l){
  __builtin_amdgcn_global_load_lds((const __attribute__((address_space(1))) void*)g,
                                   (__attribute__((address_space(3))) void*)l, 16, 0, 0);
}

__device__ __forceinline__ f32x4 mfma16(short8 a, short8 b, f32x4 c){
  return __builtin_amdgcn_mfma_f32_16x16x32_bf16(a, b, c, 0, 0, 0);
}

__device__ __forceinline__ float sigf(float x){
  return __builtin_amdgcn_rcpf(1.0f + __expf(-x));
}
__device__ __forceinline__ float tanhf_(float x){
  float e = __expf(2.0f * x);
  return 1.0f - 2.0f * __builtin_amdgcn_rcpf(e + 1.0f);
}

// ---------------- fused cast f32 -> bf16 (all 5 inputs in one launch) ----------------
__global__ __launch_bounds__(256) void k_castall(const float* __restrict__ s0, const float* __restrict__ s1,
                          const float* __restrict__ s2, const float* __restrict__ s3,
                          const float* __restrict__ s4,
                          u16* __restrict__ d0, u16* __restrict__ d1, u16* __restrict__ d2,
                          u16* __restrict__ d3, u16* __restrict__ d4)
{
  int i = blockIdx.x * 256 + threadIdx.x;   // float4 index, total 4718592
  const float* s; u16* d; int off;
  if (i < 1572864)      { s = s0; d = d0; off = i; }
  else if (i < 2752512) { s = s1; d = d1; off = i - 1572864; }
  else if (i < 2949120) { s = s2; d = d2; off = i - 2752512; }
  else if (i < 4128768) { s = s3; d = d3; off = i - 2949120; }
  else                  { s = s4; d = d4; off = i - 4128768; }
  float4 v = ((const float4*)s)[off];
  ushort4 o; o.x=f2bf(v.x); o.y=f2bf(v.y); o.z=f2bf(v.z); o.w=f2bf(v.w);
  ((ushort4*)d)[off] = o;
}

// -------- 3-stage pipelined GEMM: BM=256, BN=128, BK=64 (A[M,K] rm, B[N,K] rm) --------
// 8 waves (2M x 4N), wave tile 128x32. LDS 144KB = 3 x (A 32KB + B 16KB).
// Per K-tile t: issue 6 gld_lds for tile t+2 -> s_waitcnt vmcnt(12) (t's data landed;
// t+1,t+2 stay in flight - counted, never drained) -> barrier -> 20 ds_read + 32 MFMA
// (compiler-scheduled, buffer stable) -> lgkmcnt(0) -> barrier (WAR for t+1's staging).
// XOR swizzle: linear LDS dest + inverse-swizzled global source + swizzled ds_read.
// MODE 0: +bias1+bias2, bf16 store.  MODE 1: +bias1, exact gelu, bf16 store.
template<int MODE>
__global__ __launch_bounds__(512) void k_gemm3(
    const u16* __restrict__ A, const u16* __restrict__ B, void* __restrict__ C,
    const float* __restrict__ bias1, const float* __restrict__ bias2,
    int M, int N, int K, int lda)
{
  __shared__ __align__(16) u16 lA[3][256*64];
  __shared__ __align__(16) u16 lB[3][128*64];
  int nwg = gridDim.x;
  int bid = blockIdx.x;
  int q = nwg >> 3;
  int swz = (bid & 7) * q + (bid >> 3);   // XCD swizzle (nwg % 8 == 0)
  int nbm = M >> 8;
  int bm = swz % nbm, bn = swz / nbm;
  int tid = threadIdx.x, lane = tid & 63;
  int wv = tid >> 6;
  int wm = wv & 1, wn = wv >> 1;          // wave tile: rows wm*128, cols wn*32
  int l15 = lane & 15, lhi = lane >> 4;
  const u16* Ag = A + (size_t)(bm << 8) * lda;
  const u16* Bg = B + (size_t)bn * 128 * lda;

  // staging address tables (source col slot XORed with row&7; LDS dest linear)
  int srA[4], slA[4];
  #pragma unroll
  for (int i = 0; i < 4; ++i){
    int c = i*512 + tid;                  // A chunks: 2048
    srA[i] = c >> 3;
    slA[i] = (((c & 7) ^ (srA[i] & 7)) << 3);
  }
  int srB[2], slB[2];
  #pragma unroll
  for (int i = 0; i < 2; ++i){
    int c = i*512 + tid;                  // B chunks: 1024
    srB[i] = c >> 3;
    slB[i] = (((c & 7) ^ (srB[i] & 7)) << 3);
  }
  int axr = l15 & 7;
  int abase = (wm*128 + l15)*64;
  int bbase = (wn*32 + l15)*64;
  int rs0 = ((lhi    ) ^ axr)*8;          // k-slice 0 read slot
  int rs1 = ((lhi + 4) ^ axr)*8;          // k-slice 1 read slot

  f32x4 acc[8][2];
  #pragma unroll
  for (int i = 0; i < 8; ++i){ acc[i][0] = (f32x4){0.f,0.f,0.f,0.f}; acc[i][1] = acc[i][0]; }

  int NT = K >> 6;

#define STAGE(TT)                                                              \
  {                                                                            \
    int koff = (TT) << 6;                                                      \
    u16* dA = lA[(TT) % 3];                                                    \
    u16* dB = lB[(TT) % 3];                                                    \
    _Pragma("unroll")                                                          \
    for (int i = 0; i < 4; ++i)                                                \
      gld_lds16(Ag + (size_t)srA[i]*lda + koff + slA[i], &dA[(i*512+tid)*8]);  \
    _Pragma("unroll")                                                          \
    for (int i = 0; i < 2; ++i)                                                \
      gld_lds16(Bg + (size_t)srB[i]*lda + koff + slB[i], &dB[(i*512+tid)*8]);  \
  }

  STAGE(0)
  STAGE(1)

  for (int t = 0; t < NT; ++t){
    if (t + 2 < NT){
      STAGE(t+2)
      asm volatile("s_waitcnt vmcnt(12)" ::: "memory");
    } else if (t + 1 < NT){
      asm volatile("s_waitcnt vmcnt(6)" ::: "memory");
    } else {
      asm volatile("s_waitcnt vmcnt(0)" ::: "memory");
    }
    asm volatile("s_barrier" ::: "memory");
    __builtin_amdgcn_sched_barrier(0);

    const u16* sA = lA[t % 3];
    const u16* sB = lB[t % 3];
    short8 bf00 = *(const short8*)&sB[bbase + rs0];
    short8 bf01 = *(const short8*)&sB[bbase + rs1];
    short8 bf10 = *(const short8*)&sB[bbase + 1024 + rs0];
    short8 bf11 = *(const short8*)&sB[bbase + 1024 + rs1];
    #pragma unroll
    for (int mi = 0; mi < 8; ++mi){
      short8 a0 = *(const short8*)&sA[abase + mi*1024 + rs0];
      short8 a1 = *(const short8*)&sA[abase + mi*1024 + rs1];
      acc[mi][0] = mfma16(a0, bf00, acc[mi][0]);
      acc[mi][0] = mfma16(a1, bf01, acc[mi][0]);
      acc[mi][1] = mfma16(a0, bf10, acc[mi][1]);
      acc[mi][1] = mfma16(a1, bf11, acc[mi][1]);
    }
    asm volatile("s_waitcnt lgkmcnt(0)" ::: "memory");
    __builtin_amdgcn_sched_barrier(0);
    asm volatile("s_barrier" ::: "memory");
  }
#undef STAGE

  // epilogue
  float bsum[2];
  #pragma unroll
  for (int ni = 0; ni < 2; ++ni){
    int n = bn*128 + wn*32 + ni*16 + l15;
    bsum[ni] = (MODE == 0) ? (bias1[n] + bias2[n]) : bias1[n];
  }
  #pragma unroll
  for (int mi = 0; mi < 8; ++mi){
    #pragma unroll
    for (int r = 0; r < 4; ++r){
      int m = (bm << 8) + wm*128 + mi*16 + lhi*4 + r;
      #pragma unroll
      for (int ni = 0; ni < 2; ++ni){
        int n = bn*128 + wn*32 + ni*16 + l15;
        float v = acc[mi][ni][r] + bsum[ni];
        if (MODE == 1)
          v = 0.5f * v * (1.0f + erff(v * 0.70710678118f));
        ((u16*)C)[(size_t)m * N + n] = f2bf(v);
      }
    }
  }
}

// ---------------- 128^2 GEMM (FFN-down split-K x2; N=768 shape) ------------------
__global__ __launch_bounds__(256) void k_gemm2(const u16* __restrict__ A, const u16* __restrict__ B,
                       float* __restrict__ C, float* __restrict__ C2,
                       const float* __restrict__ bias1,
                       int M, int N, int K, int lda)
{
  __shared__ __align__(16) u16 lA[128*64];
  __shared__ __align__(16) u16 lB[128*64];
  int nwg = gridDim.x;
  int bid = blockIdx.x;
  int h2 = nwg >> 1;
  int half = (bid >= h2) ? 1 : 0;
  bid -= half ? h2 : 0;
  nwg = h2;
  int koff = half * K;
  int nbm = M >> 7;
  int q = nwg >> 3;
  int swz = (bid & 7) * q + (bid >> 3);
  int bm = swz % nbm, bn = swz / nbm;
  int tid = threadIdx.x, lane = tid & 63;
  int wv = tid >> 6;
  int wrow = (wv & 1) << 6, wcol = (wv >> 1) << 6;
  int l15 = lane & 15, lhi = lane >> 4;
  const u16* Ag = A + (size_t)bm * 128 * lda + koff;
  const u16* Bg = B + (size_t)bn * 128 * lda + koff;
  f32x4 acc[4][4];
  #pragma unroll
  for (int i=0;i<4;++i)
    #pragma unroll
    for(int j=0;j<4;++j) acc[i][j] = (f32x4){0.f,0.f,0.f,0.f};

  for (int k0 = 0; k0 < K; k0 += 64){
    #pragma unroll
    for (int i = 0; i < 4; ++i){
      int c = i*256 + tid;
      int row = c >> 3, col8 = (c & 7) << 3;
      gld_lds16(Ag + (size_t)row*lda + k0 + col8, &lA[c<<3]);
      gld_lds16(Bg + (size_t)row*lda + k0 + col8, &lB[c<<3]);
    }
    __syncthreads();
    #pragma unroll
    for (int kk = 0; kk < 2; ++kk){
      short8 af[4], bfr[4];
      #pragma unroll
      for (int f = 0; f < 4; ++f)
        af[f] = *(const short8*)&lA[(wrow + f*16 + l15)*64 + kk*32 + lhi*8];
      #pragma unroll
      for (int g = 0; g < 4; ++g)
        bfr[g] = *(const short8*)&lB[(wcol + g*16 + l15)*64 + kk*32 + lhi*8];
      #pragma unroll
      for (int f = 0; f < 4; ++f)
        #pragma unroll
        for (int g = 0; g < 4; ++g)
          acc[f][g] = mfma16(af[f], bfr[g], acc[f][g]);
    }
    __syncthreads();
  }
  float* Cw = half ? C2 : C;
  #pragma unroll
  for (int f = 0; f < 4; ++f){
    #pragma unroll
    for (int r = 0; r < 4; ++r){
      int m = bm*128 + wrow + f*16 + lhi*4 + r;
      #pragma unroll
      for (int g = 0; g < 4; ++g){
        int n = bn*128 + wcol + g*16 + l15;
        float v = acc[f][g][r];
        if (!half) v += bias1[n];
        Cw[(size_t)m * N + n] = v;
      }
    }
  }
}

// ---------------- LSTM scan: 48 WGs (dir x 4 batch-groups), 512 threads ----------------
__global__ __launch_bounds__(512) void k_scan(const u16* __restrict__ whh, const u16* __restrict__ xp,
                       u16* __restrict__ cat)
{
  __shared__ __align__(16) u16 hb[2][4*144];   // h[batch][dim], rows padded to 144 u16
  int bid = blockIdx.x;
  int d = bid >> 2, bg = bid & 3;
  int tid = threadIdx.x, lane = tid & 63, w = tid >> 6;
  int l15 = lane & 15, lhi = lane >> 4;

  u16* hbf = (u16*)hb;
  for (int i = tid; i < 2*4*144; i += 512) hbf[i] = 0;

  short8 wf[4][4];
  #pragma unroll
  for (int g = 0; g < 4; ++g)
    #pragma unroll
    for (int kk = 0; kk < 4; ++kk)
      wf[g][kk] = *(const short8*)(whh + ((size_t)d*512 + g*128 + w*16 + l15)*128 + kk*32 + lhi*8);

  int b = bg*4 + lhi;
  int dim = w*16 + l15;
  bool fwd = (d < 6);
  const u16* zrow = xp + (size_t)b*512*6144 + d*512 + dim;  // + s*6144 + gate*128

  u32 Zi[4], Zf[4], Zg[4], Zo[4];
  #pragma unroll
  for (int j = 0; j < 4; ++j){
    int s = fwd ? j : 511 - j;
    const u16* p = zrow + (size_t)s*6144;
    Zi[j] = p[0]; Zf[j] = p[128]; Zg[j] = p[256]; Zo[j] = p[384];
  }

  f32x4 a0={0.f,0.f,0.f,0.f}, a1=a0, a2=a0, a3=a0;
  float cr = 0.f;
  int head = fwd ? d : d - 6;
  int posoff = fwd ? 0 : 128;
  size_t catlane = (size_t)b*512*1536 + head*256 + posoff + dim;
  int catoff = fwd ? 0 : 511*1536;
  int catstep = fwd ? 1536 : -1536;

  int hrd = (l15 >> 2)*144 + lhi*8;
  int hwr = lhi*144 + dim;

  __syncthreads();

#define SCAN_STEP(T, RB, WB, S)                                                \
  {                                                                            \
    short8 hf0 = *(const short8*)&hb[RB][hrd + 0*32];                          \
    short8 hf1 = *(const short8*)&hb[RB][hrd + 1*32];                          \
    short8 hf2 = *(const short8*)&hb[RB][hrd + 2*32];                          \
    short8 hf3 = *(const short8*)&hb[RB][hrd + 3*32];                          \
    a0[0] = bf2f32(Zi[S]); a1[0] = bf2f32(Zf[S]);                              \
    a2[0] = bf2f32(Zg[S]); a3[0] = bf2f32(Zo[S]);                              \
    int t4 = (T) + 4; if (t4 > 511) t4 = 511;                                  \
    int s4 = fwd ? t4 : 511 - t4;                                              \
    const u16* pf = zrow + (size_t)s4*6144;                                    \
    Zi[S] = pf[0]; Zf[S] = pf[128]; Zg[S] = pf[256]; Zo[S] = pf[384];          \
    a2 = mfma16(hf0, wf[2][0], a2); a0 = mfma16(hf0, wf[0][0], a0);            \
    a1 = mfma16(hf0, wf[1][0], a1); a3 = mfma16(hf0, wf[3][0], a3);            \
    a2 = mfma16(hf1, wf[2][1], a2); a0 = mfma16(hf1, wf[0][1], a0);            \
    a1 = mfma16(hf1, wf[1][1], a1); a3 = mfma16(hf1, wf[3][1], a3);            \
    a2 = mfma16(hf2, wf[2][2], a2); a0 = mfma16(hf2, wf[0][2], a0);            \
    a1 = mfma16(hf2, wf[1][2], a1); a3 = mfma16(hf2, wf[3][2], a3);            \
    a2 = mfma16(hf3, wf[2][3], a2); a0 = mfma16(hf3, wf[0][3], a0);            \
    a1 = mfma16(hf3, wf[1][3], a1); a3 = mfma16(hf3, wf[3][3], a3);            \
    float tg = tanhf_(a2[0]);                                                  \
    float fi = sigf(a0[0]), ff = sigf(a1[0]), fo = sigf(a3[0]);                \
    cr = ff*cr + fi*tg;                                                        \
    float hv = fo * tanhf_(cr);                                                \
    u32 hp32;                                                                  \
    asm("v_cvt_pk_bf16_f32 %0, %1, %2" : "=v"(hp32) : "v"(hv), "v"(hv));       \
    u16 hp = (u16)hp32;                                                        \
    hb[WB][hwr] = hp;                                                          \
    asm volatile("s_waitcnt lgkmcnt(0)" ::: "memory");                         \
    __builtin_amdgcn_s_barrier();                                              \
    cat[catlane + catoff] = hp;                                                \
    catoff += catstep;                                                         \
  }

  for (int t = 0; t < 512; t += 4){
    SCAN_STEP(t,   0, 1, 0)
    SCAN_STEP(t+1, 1, 0, 1)
    SCAN_STEP(t+2, 0, 1, 2)
    SCAN_STEP(t+3, 1, 0, 3)
  }
#undef SCAN_STEP
}

// ---------------- residual + LayerNorm (sums two split-K partials) ----------------
__global__ __launch_bounds__(256) void k_ln(const float* __restrict__ emb, const float* __restrict__ p0,
                     const float* __restrict__ p1,
                     const float* __restrict__ gamma, const float* __restrict__ beta,
                     float* __restrict__ out)
{
  int row = blockIdx.x, tid = threadIdx.x;
  const float* pe = emb + (size_t)row * 768;
  const float* pa = p0 + (size_t)row * 768;
  const float* pb = p1 + (size_t)row * 768;
  float v0 = pe[tid]     + pa[tid]     + pb[tid];
  float v1 = pe[tid+256] + pa[tid+256] + pb[tid+256];
  float v2 = pe[tid+512] + pa[tid+512] + pb[tid+512];
  float s = v0+v1+v2, s2 = v0*v0+v1*v1+v2*v2;
  #pragma unroll
  for (int o = 32; o > 0; o >>= 1){ s += __shfl_down(s, o); s2 += __shfl_down(s2, o); }
  __shared__ float rs[4], rq[4];
  int wv = tid >> 6;
  if ((tid & 63) == 0){ rs[wv] = s; rq[wv] = s2; }
  __syncthreads();
  s = rs[0]+rs[1]+rs[2]+rs[3];
  s2 = rq[0]+rq[1]+rq[2]+rq[3];
  float mu = s * (1.0f/768.0f);
  float var = s2 * (1.0f/768.0f) - mu*mu;
  float rr = rsqrtf(var + 1e-5f);
  float* po = out + (size_t)row * 768;
  po[tid]     = (v0-mu)*rr*gamma[tid]     + beta[tid];
  po[tid+256] = (v1-mu)*rr*gamma[tid+256] + beta[tid+256];
  po[tid+512] = (v2-mu)*rr*gamma[tid+512] + beta[tid+512];
}

extern "C" void kernel_launch(void* const* d_in, const int* in_sizes, int n_in,
                              void* d_out, int out_size, void* d_ws, size_t ws_size,
                              hipStream_t stream)
{
  const float* emb   = (const float*)d_in[0];
  const float* W_ih  = (const float*)d_in[1];
  const float* W_hh  = (const float*)d_in[2];
  const float* b_ih  = (const float*)d_in[3];
  const float* b_hh  = (const float*)d_in[4];
  const float* W_int = (const float*)d_in[5];
  const float* b_int = (const float*)d_in[6];
  const float* W_out = (const float*)d_in[7];
  const float* b_out = (const float*)d_in[8];
  const float* gamma = (const float*)d_in[9];
  const float* beta  = (const float*)d_in[10];
  float* out = (float*)d_out;

  char* ws = (char*)d_ws;
  u16* embb  = (u16*)(ws + 0);           // 12,582,912
  u16* wihb  = (u16*)(ws + 12582912);    //  9,437,184
  u16* whhb  = (u16*)(ws + 22020096);    //  1,572,864
  u16* wintb = (u16*)(ws + 23592960);    //  9,437,184
  u16* woutb = (u16*)(ws + 33030144);    //  4,718,592
  u16* catb  = (u16*)(ws + 37748736);    // 25,165,824 (dead after GEMM1)
  float* proj1=(float*)(ws + 37748736);  // 25,165,824 (overlays catb)
  u16* xp    = (u16*)(ws + 62914560);    // 100,663,296 (dead after scan)
  u16* interb= (u16*)(ws + 62914560);    // 50,331,648 (reuses xp)
  float* proj0=(float*)(ws + 113246208); // 25,165,824 (reuses xp tail)

  // fused casts (emb, W_ih, W_hh, W_int, W_out)
  hipLaunchKernelGGL(k_castall, dim3(18432), dim3(256), 0, stream,
                     emb, W_ih, W_hh, W_int, W_out, embb, wihb, whhb, wintb, woutb);

  // x-projection: [8192,768] x [6144,768]^T -> xp row-major (bias baked in)
  hipLaunchKernelGGL((k_gemm3<0>), dim3(1536), dim3(512), 0, stream,
                     embb, wihb, (void*)xp, b_ih, b_hh, 8192, 6144, 768, 768);
  // sequential BiLSTM scan -> cat [16,512,1536] bf16
  hipLaunchKernelGGL(k_scan, dim3(48), dim3(512), 0, stream, whhb, xp, catb);
  // FFN up + gelu: [8192,1536] x [3072,1536]^T -> inter bf16
  hipLaunchKernelGGL((k_gemm3<1>), dim3(768), dim3(512), 0, stream,
                     catb, wintb, (void*)interb, b_int, nullptr, 8192, 3072, 1536, 1536);
  // FFN down, split-K x2: [8192,3072] x [768,3072]^T -> proj0 (half0) + proj1 (half1)
  hipLaunchKernelGGL(k_gemm2, dim3(768), dim3(256), 0, stream,
                     interb, woutb, proj0, proj1, b_out, 8192, 768, 1536, 3072);
  // residual + LayerNorm
  hipLaunchKernelGGL(k_ln, dim3(8192), dim3(256), 0, stream, emb, proj0, proj1, gamma, beta, out);
}

// Round 10
// 523.575 us; speedup vs baseline: 1.1609x; 1.1609x over previous
//
#include <hip/hip_runtime.h>

typedef __attribute__((ext_vector_type(4))) float f32x4;
typedef __attribute__((ext_vector_type(8))) short short8;
typedef unsigned short u16;
typedef unsigned int u32;

__device__ __forceinline__ u16 f2bf(float f){
  u32 x = __float_as_uint(f);
  u32 r = x + 0x7fffu + ((x >> 16) & 1u);
  return (u16)(r >> 16);
}
__device__ __forceinline__ float bf2f32(u32 u){ return __uint_as_float(u << 16); }

__device__ __forceinline__ void gld_lds16(const u16* g, u16* l){
  __builtin_amdgcn_global_load_lds((const __attribute__((address_space(1))) void*)g,
                                   (__attribute__((address_space(3))) void*)l, 16, 0, 0);
}

__device__ __forceinline__ f32x4 mfma16(short8 a, short8 b, f32x4 c){
  return __builtin_amdgcn_mfma_f32_16x16x32_bf16(a, b, c, 0, 0, 0);
}

__device__ __forceinline__ float sigf(float x){
  return __builtin_amdgcn_rcpf(1.0f + __expf(-x));
}
__device__ __forceinline__ float tanhf_(float x){
  float e = __expf(2.0f * x);
  return 1.0f - 2.0f * __builtin_amdgcn_rcpf(e + 1.0f);
}

// ---------------- fused cast f32 -> bf16 (all 5 inputs in one launch) ----------------
__global__ __launch_bounds__(256) void k_castall(const float* __restrict__ s0, const float* __restrict__ s1,
                          const float* __restrict__ s2, const float* __restrict__ s3,
                          const float* __restrict__ s4,
                          u16* __restrict__ d0, u16* __restrict__ d1, u16* __restrict__ d2,
                          u16* __restrict__ d3, u16* __restrict__ d4)
{
  int i = blockIdx.x * 256 + threadIdx.x;   // float4 index, total 4718592
  const float* s; u16* d; int off;
  if (i < 1572864)      { s = s0; d = d0; off = i; }
  else if (i < 2752512) { s = s1; d = d1; off = i - 1572864; }
  else if (i < 2949120) { s = s2; d = d2; off = i - 2752512; }
  else if (i < 4128768) { s = s3; d = d3; off = i - 2949120; }
  else                  { s = s4; d = d4; off = i - 4128768; }
  float4 v = ((const float4*)s)[off];
  ushort4 o; o.x=f2bf(v.x); o.y=f2bf(v.y); o.z=f2bf(v.z); o.w=f2bf(v.w);
  ((ushort4*)d)[off] = o;
}

// ---------------- 256^2-tile phase-split GEMM (A[M,K] rm, B[N,K] rm = B^T) -------------
// R8 structure (proven): 8 waves (2M x 4N), BK=64, LDS 128KB double-buffered,
// 4 phases/K-tile with interleaved staging, XOR swizzle both-sides.
// NEW (R10): L2-grouped grid mapping - within each XCD chunk, 8bm x nbn groups so a
// resident cohort (32 WGs/XCD) covers 8x4 tiles = 12 panels (L2-resident) instead of 33.
// MODE 0: +bias1+bias2, bf16 store.  MODE 1: +bias1, exact gelu, bf16 store.
template<int MODE>
__global__ __launch_bounds__(512, 2) void k_gemm256(
    const u16* __restrict__ A, const u16* __restrict__ B, void* __restrict__ C,
    const float* __restrict__ bias1, const float* __restrict__ bias2,
    int M, int N, int K, int lda)
{
  __shared__ __align__(16) u16 lA[2][256*64];
  __shared__ __align__(16) u16 lB[2][256*64];
  int nwg = gridDim.x;
  int bid = blockIdx.x;
  int q = nwg >> 3;
  int swz = (bid & 7) * q + (bid >> 3);   // XCD swizzle (nwg % 8 == 0)
  int nbn = N >> 8;
  int grp = nbn << 3;                     // group = 8 bm rows x nbn cols
  int gid = swz / grp, rem = swz % grp;
  int bm = (gid << 3) + (rem & 7), bn = rem >> 3;
  int tid = threadIdx.x, lane = tid & 63;
  int wv = tid >> 6;
  int wm = wv & 1, wn = wv >> 1;          // wave tile: rows wm*128, cols wn*64
  int l15 = lane & 15, lhi = lane >> 4;
  const u16* Ag = A + (size_t)(bm << 8) * lda;
  const u16* Bg = B + (size_t)(bn << 8) * lda;

  // staging: chunk c = i*512+tid of 16B; row=c>>3, slot=c&7; source slot ^= row&7
  int srow[4], ssl[4];
  #pragma unroll
  for (int i = 0; i < 4; ++i){
    int c = i*512 + tid;
    srow[i] = c >> 3;
    ssl[i] = (((c & 7) ^ (srow[i] & 7)) << 3);   // u16 offset in row
  }
  // swizzled read offsets (u16); frag (mi|ni) at +1024*idx
  int axr = l15 & 7;
  int aoff0 = (wm*128 + l15)*64 + ((lhi    ) ^ axr)*8;
  int aoff1 = (wm*128 + l15)*64 + ((lhi + 4) ^ axr)*8;
  int boff0 = (wn*64  + l15)*64 + ((lhi    ) ^ axr)*8;
  int boff1 = (wn*64  + l15)*64 + ((lhi + 4) ^ axr)*8;

  f32x4 acc[8][4];
  #pragma unroll
  for (int i = 0; i < 8; ++i)
    #pragma unroll
    for (int j = 0; j < 4; ++j)
      acc[i][j] = (f32x4){0.f,0.f,0.f,0.f};

  int NT = K >> 6;

  // prologue: stage tile 0 into buffer 0, full drain once
  #pragma unroll
  for (int i = 0; i < 4; ++i)
    gld_lds16(Ag + (size_t)srow[i]*lda + ssl[i], &lA[0][(i*512+tid)*8]);
  #pragma unroll
  for (int i = 0; i < 4; ++i)
    gld_lds16(Bg + (size_t)srow[i]*lda + ssl[i], &lB[0][(i*512+tid)*8]);
  asm volatile("s_waitcnt vmcnt(0)" ::: "memory");
  __builtin_amdgcn_s_barrier();

  for (int t = 0; t < NT; ++t){
    int bp = t & 1;
    const u16* sA = lA[bp];
    const u16* sB = lB[bp];
    u16* dA = lA[bp^1];
    u16* dB = lB[bp^1];
    int k1 = (t + 1) << 6;
    bool more = (t + 1 < NT);
    short8 bf[4][2];
    #pragma unroll
    for (int p = 0; p < 4; ++p){
      if (p == 0){
        #pragma unroll
        for (int ni = 0; ni < 4; ++ni){
          bf[ni][0] = *(const short8*)&sB[boff0 + ni*1024];
          bf[ni][1] = *(const short8*)&sB[boff1 + ni*1024];
        }
      }
      short8 a00 = *(const short8*)&sA[aoff0 + (2*p)*1024];
      short8 a01 = *(const short8*)&sA[aoff1 + (2*p)*1024];
      short8 a10 = *(const short8*)&sA[aoff0 + (2*p+1)*1024];
      short8 a11 = *(const short8*)&sA[aoff1 + (2*p+1)*1024];
      if (more && p == 0){
        #pragma unroll
        for (int i = 0; i < 4; ++i)
          gld_lds16(Ag + (size_t)srow[i]*lda + k1 + ssl[i], &dA[(i*512+tid)*8]);
      }
      if (more && p == 1){
        #pragma unroll
        for (int i = 0; i < 4; ++i)
          gld_lds16(Bg + (size_t)srow[i]*lda + k1 + ssl[i], &dB[(i*512+tid)*8]);
      }
      __builtin_amdgcn_s_barrier();
      asm volatile("s_waitcnt lgkmcnt(0)" ::: "memory");
      __builtin_amdgcn_sched_barrier(0);
      __builtin_amdgcn_s_setprio(1);
      #pragma unroll
      for (int ni = 0; ni < 4; ++ni){
        acc[2*p  ][ni] = mfma16(a00, bf[ni][0], acc[2*p  ][ni]);
        acc[2*p  ][ni] = mfma16(a01, bf[ni][1], acc[2*p  ][ni]);
        acc[2*p+1][ni] = mfma16(a10, bf[ni][0], acc[2*p+1][ni]);
        acc[2*p+1][ni] = mfma16(a11, bf[ni][1], acc[2*p+1][ni]);
      }
      __builtin_amdgcn_s_setprio(0);
      if (p == 3){
        asm volatile("s_waitcnt vmcnt(0)" ::: "memory");
      }
      __builtin_amdgcn_s_barrier();
    }
  }

  // epilogue
  float bsum[4];
  #pragma unroll
  for (int ni = 0; ni < 4; ++ni){
    int n = (bn << 8) + wn*64 + ni*16 + l15;
    bsum[ni] = (MODE == 0) ? (bias1[n] + bias2[n]) : bias1[n];
  }
  #pragma unroll
  for (int mi = 0; mi < 8; ++mi){
    #pragma unroll
    for (int r = 0; r < 4; ++r){
      int m = (bm << 8) + wm*128 + mi*16 + lhi*4 + r;
      #pragma unroll
      for (int ni = 0; ni < 4; ++ni){
        int n = (bn << 8) + wn*64 + ni*16 + l15;
        float v = acc[mi][ni][r] + bsum[ni];
        if (MODE == 1)
          v = 0.5f * v * (1.0f + erff(v * 0.70710678118f));
        ((u16*)C)[(size_t)m * N + n] = f2bf(v);
      }
    }
  }
}

// ---------------- 128^2 GEMM (FFN-down split-K x2; N=768 shape) ------------------
__global__ __launch_bounds__(256) void k_gemm2(const u16* __restrict__ A, const u16* __restrict__ B,
                       float* __restrict__ C, float* __restrict__ C2,
                       const float* __restrict__ bias1,
                       int M, int N, int K, int lda)
{
  __shared__ __align__(16) u16 lA[128*64];
  __shared__ __align__(16) u16 lB[128*64];
  int nwg = gridDim.x;
  int bid = blockIdx.x;
  int h2 = nwg >> 1;
  int half = (bid >= h2) ? 1 : 0;
  bid -= half ? h2 : 0;
  nwg = h2;
  int koff = half * K;
  int q = nwg >> 3;
  int swz = (bid & 7) * q + (bid >> 3);
  int nbn = N >> 7;
  int grp = nbn << 3;                     // 8 bm x nbn groups (L2 cohort 8x4)
  int gid = swz / grp, rem = swz % grp;
  int bm = (gid << 3) + (rem & 7), bn = rem >> 3;
  int tid = threadIdx.x, lane = tid & 63;
  int wv = tid >> 6;
  int wrow = (wv & 1) << 6, wcol = (wv >> 1) << 6;
  int l15 = lane & 15, lhi = lane >> 4;
  const u16* Ag = A + (size_t)bm * 128 * lda + koff;
  const u16* Bg = B + (size_t)bn * 128 * lda + koff;
  f32x4 acc[4][4];
  #pragma unroll
  for (int i=0;i<4;++i)
    #pragma unroll
    for(int j=0;j<4;++j) acc[i][j] = (f32x4){0.f,0.f,0.f,0.f};

  for (int k0 = 0; k0 < K; k0 += 64){
    #pragma unroll
    for (int i = 0; i < 4; ++i){
      int c = i*256 + tid;
      int row = c >> 3, col8 = (c & 7) << 3;
      gld_lds16(Ag + (size_t)row*lda + k0 + col8, &lA[c<<3]);
      gld_lds16(Bg + (size_t)row*lda + k0 + col8, &lB[c<<3]);
    }
    __syncthreads();
    #pragma unroll
    for (int kk = 0; kk < 2; ++kk){
      short8 af[4], bfr[4];
      #pragma unroll
      for (int f = 0; f < 4; ++f)
        af[f] = *(const short8*)&lA[(wrow + f*16 + l15)*64 + kk*32 + lhi*8];
      #pragma unroll
      for (int g = 0; g < 4; ++g)
        bfr[g] = *(const short8*)&lB[(wcol + g*16 + l15)*64 + kk*32 + lhi*8];
      #pragma unroll
      for (int f = 0; f < 4; ++f)
        #pragma unroll
        for (int g = 0; g < 4; ++g)
          acc[f][g] = mfma16(af[f], bfr[g], acc[f][g]);
    }
    __syncthreads();
  }
  float* Cw = half ? C2 : C;
  #pragma unroll
  for (int f = 0; f < 4; ++f){
    #pragma unroll
    for (int r = 0; r < 4; ++r){
      int m = bm*128 + wrow + f*16 + lhi*4 + r;
      #pragma unroll
      for (int g = 0; g < 4; ++g){
        int n = bn*128 + wcol + g*16 + l15;
        float v = acc[f][g][r];
        if (!half) v += bias1[n];
        Cw[(size_t)m * N + n] = v;
      }
    }
  }
}

// ---------------- LSTM scan: 48 WGs (dir x 4 batch-groups), 512 threads ----------------
__global__ __launch_bounds__(512) void k_scan(const u16* __restrict__ whh, const u16* __restrict__ xp,
                       u16* __restrict__ cat)
{
  __shared__ __align__(16) u16 hb[2][4*144];   // h[batch][dim], rows padded to 144 u16
  int bid = blockIdx.x;
  int d = bid >> 2, bg = bid & 3;
  int tid = threadIdx.x, lane = tid & 63, w = tid >> 6;
  int l15 = lane & 15, lhi = lane >> 4;

  u16* hbf = (u16*)hb;
  for (int i = tid; i < 2*4*144; i += 512) hbf[i] = 0;

  short8 wf[4][4];
  #pragma unroll
  for (int g = 0; g < 4; ++g)
    #pragma unroll
    for (int kk = 0; kk < 4; ++kk)
      wf[g][kk] = *(const short8*)(whh + ((size_t)d*512 + g*128 + w*16 + l15)*128 + kk*32 + lhi*8);

  int b = bg*4 + lhi;
  int dim = w*16 + l15;
  bool fwd = (d < 6);
  const u16* zrow = xp + (size_t)b*512*6144 + d*512 + dim;  // + s*6144 + gate*128

  u32 Zi[4], Zf[4], Zg[4], Zo[4];
  #pragma unroll
  for (int j = 0; j < 4; ++j){
    int s = fwd ? j : 511 - j;
    const u16* p = zrow + (size_t)s*6144;
    Zi[j] = p[0]; Zf[j] = p[128]; Zg[j] = p[256]; Zo[j] = p[384];
  }

  f32x4 a0={0.f,0.f,0.f,0.f}, a1=a0, a2=a0, a3=a0;
  float cr = 0.f;
  int head = fwd ? d : d - 6;
  int posoff = fwd ? 0 : 128;
  size_t catlane = (size_t)b*512*1536 + head*256 + posoff + dim;
  int catoff = fwd ? 0 : 511*1536;
  int catstep = fwd ? 1536 : -1536;

  int hrd = (l15 >> 2)*144 + lhi*8;
  int hwr = lhi*144 + dim;

  __syncthreads();

#define SCAN_STEP(T, RB, WB, S)                                                \
  {                                                                            \
    short8 hf0 = *(const short8*)&hb[RB][hrd + 0*32];                          \
    short8 hf1 = *(const short8*)&hb[RB][hrd + 1*32];                          \
    short8 hf2 = *(const short8*)&hb[RB][hrd + 2*32];                          \
    short8 hf3 = *(const short8*)&hb[RB][hrd + 3*32];                          \
    a0[0] = bf2f32(Zi[S]); a1[0] = bf2f32(Zf[S]);                              \
    a2[0] = bf2f32(Zg[S]); a3[0] = bf2f32(Zo[S]);                              \
    int t4 = (T) + 4; if (t4 > 511) t4 = 511;                                  \
    int s4 = fwd ? t4 : 511 - t4;                                              \
    const u16* pf = zrow + (size_t)s4*6144;                                    \
    Zi[S] = pf[0]; Zf[S] = pf[128]; Zg[S] = pf[256]; Zo[S] = pf[384];          \
    a2 = mfma16(hf0, wf[2][0], a2); a0 = mfma16(hf0, wf[0][0], a0);            \
    a1 = mfma16(hf0, wf[1][0], a1); a3 = mfma16(hf0, wf[3][0], a3);            \
    a2 = mfma16(hf1, wf[2][1], a2); a0 = mfma16(hf1, wf[0][1], a0);            \
    a1 = mfma16(hf1, wf[1][1], a1); a3 = mfma16(hf1, wf[3][1], a3);            \
    a2 = mfma16(hf2, wf[2][2], a2); a0 = mfma16(hf2, wf[0][2], a0);            \
    a1 = mfma16(hf2, wf[1][2], a1); a3 = mfma16(hf2, wf[3][2], a3);            \
    a2 = mfma16(hf3, wf[2][3], a2); a0 = mfma16(hf3, wf[0][3], a0);            \
    a1 = mfma16(hf3, wf[1][3], a1); a3 = mfma16(hf3, wf[3][3], a3);            \
    float tg = tanhf_(a2[0]);                                                  \
    float fi = sigf(a0[0]), ff = sigf(a1[0]), fo = sigf(a3[0]);                \
    cr = ff*cr + fi*tg;                                                        \
    float hv = fo * tanhf_(cr);                                                \
    u32 hp32;                                                                  \
    asm("v_cvt_pk_bf16_f32 %0, %1, %2" : "=v"(hp32) : "v"(hv), "v"(hv));       \
    u16 hp = (u16)hp32;                                                        \
    hb[WB][hwr] = hp;                                                          \
    asm volatile("s_waitcnt lgkmcnt(0)" ::: "memory");                         \
    __builtin_amdgcn_s_barrier();                                              \
    cat[catlane + catoff] = hp;                                                \
    catoff += catstep;                                                         \
  }

  for (int t = 0; t < 512; t += 4){
    SCAN_STEP(t,   0, 1, 0)
    SCAN_STEP(t+1, 1, 0, 1)
    SCAN_STEP(t+2, 0, 1, 2)
    SCAN_STEP(t+3, 1, 0, 3)
  }
#undef SCAN_STEP
}

// ---------------- residual + LayerNorm (sums two split-K partials) ----------------
__global__ __launch_bounds__(256) void k_ln(const float* __restrict__ emb, const float* __restrict__ p0,
                     const float* __restrict__ p1,
                     const float* __restrict__ gamma, const float* __restrict__ beta,
                     float* __restrict__ out)
{
  int row = blockIdx.x, tid = threadIdx.x;
  const float* pe = emb + (size_t)row * 768;
  const float* pa = p0 + (size_t)row * 768;
  const float* pb = p1 + (size_t)row * 768;
  float v0 = pe[tid]     + pa[tid]     + pb[tid];
  float v1 = pe[tid+256] + pa[tid+256] + pb[tid+256];
  float v2 = pe[tid+512] + pa[tid+512] + pb[tid+512];
  float s = v0+v1+v2, s2 = v0*v0+v1*v1+v2*v2;
  #pragma unroll
  for (int o = 32; o > 0; o >>= 1){ s += __shfl_down(s, o); s2 += __shfl_down(s2, o); }
  __shared__ float rs[4], rq[4];
  int wv = tid >> 6;
  if ((tid & 63) == 0){ rs[wv] = s; rq[wv] = s2; }
  __syncthreads();
  s = rs[0]+rs[1]+rs[2]+rs[3];
  s2 = rq[0]+rq[1]+rq[2]+rq[3];
  float mu = s * (1.0f/768.0f);
  float var = s2 * (1.0f/768.0f) - mu*mu;
  float rr = rsqrtf(var + 1e-5f);
  float* po = out + (size_t)row * 768;
  po[tid]     = (v0-mu)*rr*gamma[tid]     + beta[tid];
  po[tid+256] = (v1-mu)*rr*gamma[tid+256] + beta[tid+256];
  po[tid+512] = (v2-mu)*rr*gamma[tid+512] + beta[tid+512];
}

extern "C" void kernel_launch(void* const* d_in, const int* in_sizes, int n_in,
                              void* d_out, int out_size, void* d_ws, size_t ws_size,
                              hipStream_t stream)
{
  const float* emb   = (const float*)d_in[0];
  const float* W_ih  = (const float*)d_in[1];
  const float* W_hh  = (const float*)d_in[2];
  const float* b_ih  = (const float*)d_in[3];
  const float* b_hh  = (const float*)d_in[4];
  const float* W_int = (const float*)d_in[5];
  const float* b_int = (const float*)d_in[6];
  const float* W_out = (const float*)d_in[7];
  const float* b_out = (const float*)d_in[8];
  const float* gamma = (const float*)d_in[9];
  const float* beta  = (const float*)d_in[10];
  float* out = (float*)d_out;

  char* ws = (char*)d_ws;
  u16* embb  = (u16*)(ws + 0);           // 12,582,912
  u16* wihb  = (u16*)(ws + 12582912);    //  9,437,184
  u16* whhb  = (u16*)(ws + 22020096);    //  1,572,864
  u16* wintb = (u16*)(ws + 23592960);    //  9,437,184
  u16* woutb = (u16*)(ws + 33030144);    //  4,718,592
  u16* catb  = (u16*)(ws + 37748736);    // 25,165,824 (dead after GEMM1)
  float* proj1=(float*)(ws + 37748736);  // 25,165,824 (overlays catb)
  u16* xp    = (u16*)(ws + 62914560);    // 100,663,296 (dead after scan)
  u16* interb= (u16*)(ws + 62914560);    // 50,331,648 (reuses xp)
  float* proj0=(float*)(ws + 113246208); // 25,165,824 (reuses xp tail)

  // fused casts (emb, W_ih, W_hh, W_int, W_out)
  hipLaunchKernelGGL(k_castall, dim3(18432), dim3(256), 0, stream,
                     emb, W_ih, W_hh, W_int, W_out, embb, wihb, whhb, wintb, woutb);

  // x-projection: [8192,768] x [6144,768]^T -> xp row-major (bias baked in)
  hipLaunchKernelGGL((k_gemm256<0>), dim3(768), dim3(512), 0, stream,
                     embb, wihb, (void*)xp, b_ih, b_hh, 8192, 6144, 768, 768);
  // sequential BiLSTM scan -> cat [16,512,1536] bf16
  hipLaunchKernelGGL(k_scan, dim3(48), dim3(512), 0, stream, whhb, xp, catb);
  // FFN up + gelu: [8192,1536] x [3072,1536]^T -> inter bf16
  hipLaunchKernelGGL((k_gemm256<1>), dim3(384), dim3(512), 0, stream,
                     catb, wintb, (void*)interb, b_int, nullptr, 8192, 3072, 1536, 1536);
  // FFN down, split-K x2: [8192,3072] x [768,3072]^T -> proj0 (half0) + proj1 (half1)
  hipLaunchKernelGGL(k_gemm2, dim3(768), dim3(256), 0, stream,
                     interb, woutb, proj0, proj1, b_out, 8192, 768, 1536, 3072);
  // residual + LayerNorm
  hipLaunchKernelGGL(k_ln, dim3(8192), dim3(256), 0, stream, emb, proj0, proj1, gamma, beta, out);
}

// Round 11
// 506.095 us; speedup vs baseline: 1.2010x; 1.0345x over previous
//
#include <hip/hip_runtime.h>

typedef __attribute__((ext_vector_type(4))) float f32x4;
typedef __attribute__((ext_vector_type(8))) short short8;
typedef unsigned short u16;
typedef unsigned int u32;

__device__ __forceinline__ u16 f2bf(float f){
  u32 x = __float_as_uint(f);
  u32 r = x + 0x7fffu + ((x >> 16) & 1u);
  return (u16)(r >> 16);
}
__device__ __forceinline__ float bf2f32(u32 u){ return __uint_as_float(u << 16); }

__device__ __forceinline__ void gld_lds16(const u16* g, u16* l){
  __builtin_amdgcn_global_load_lds((const __attribute__((address_space(1))) void*)g,
                                   (__attribute__((address_space(3))) void*)l, 16, 0, 0);
}

__device__ __forceinline__ f32x4 mfma16(short8 a, short8 b, f32x4 c){
  return __builtin_amdgcn_mfma_f32_16x16x32_bf16(a, b, c, 0, 0, 0);
}

__device__ __forceinline__ float sigf(float x){
  return __builtin_amdgcn_rcpf(1.0f + __expf(-x));
}
__device__ __forceinline__ float tanhf_(float x){
  float e = __expf(2.0f * x);
  return 1.0f - 2.0f * __builtin_amdgcn_rcpf(e + 1.0f);
}

// ---------------- fused cast f32 -> bf16 (emb, W_hh, W_int, W_out) ----------------
__global__ __launch_bounds__(256) void k_castall(const float* __restrict__ s0, const float* __restrict__ s1,
                          const float* __restrict__ s2, const float* __restrict__ s3,
                          u16* __restrict__ d0, u16* __restrict__ d1, u16* __restrict__ d2,
                          u16* __restrict__ d3)
{
  int i = blockIdx.x * 256 + threadIdx.x;   // float4 index, total 3538944
  const float* s; u16* d; int off;
  if (i < 1572864)      { s = s0; d = d0; off = i; }
  else if (i < 1769472) { s = s1; d = d1; off = i - 1572864; }
  else if (i < 2949120) { s = s2; d = d2; off = i - 1769472; }
  else                  { s = s3; d = d3; off = i - 2949120; }
  float4 v = ((const float4*)s)[off];
  ushort4 o; o.x=f2bf(v.x); o.y=f2bf(v.y); o.z=f2bf(v.z); o.w=f2bf(v.w);
  ((ushort4*)d)[off] = o;
}

// ---------------- W_ih permute-cast: dest row n' = d*512 + dim*4 + gate ----------------
// src row = d*512 + gate*128 + dim. Makes GEMM0's row-major xp give the scan its
// 4 gate values contiguously (one ushort4 per lane per step).
__global__ __launch_bounds__(192) void k_permw(const float* __restrict__ wih, u16* __restrict__ dst)
{
  int np = blockIdx.x;            // dest row 0..6143
  int d = np >> 9, r = np & 511;
  int src = d*512 + (r & 3)*128 + (r >> 2);
  float4 v = ((const float4*)(wih + (size_t)src*768))[threadIdx.x];
  ushort4 o; o.x=f2bf(v.x); o.y=f2bf(v.y); o.z=f2bf(v.z); o.w=f2bf(v.w);
  ((ushort4*)(dst + (size_t)np*768))[threadIdx.x] = o;
}

// -------- unified pipelined GEMM: BM=256, BN=192, BK=64 (A[M,K] rm, B[N,K] rm) --------
// 8 waves (2M x 4N), wave tile 128x48. LDS 136KB: A 2-buf (64KB) + B 3-buf (72KB).
// R8's proven 4-phase skeleton per K-tile; staging: p0 issues A(t+1) (gap 4 phases),
// p1 issues B(t+2) (gap 7 phases); p3 waits COUNTED vmcnt(3) (A(t+1)+B(t+1) landed,
// B(t+2) stays in flight) - never drains to 0 in steady state.
// XOR swizzle both-sides (linear gld_lds dest + inv-swizzled source + swizzled read).
// MODE 0: +b_ih+b_hh gathered via perm(n), bf16 store (xp).
// MODE 1: +bias1, exact gelu, bf16 store.
// MODE 2: split-K by grid half; +bias1 (half0); f32 store to C (half0) / C2 (half1).
template<int MODE>
__global__ __launch_bounds__(512) void k_gemm3(
    const u16* __restrict__ A, const u16* __restrict__ B,
    void* __restrict__ C, void* __restrict__ C2,
    const float* __restrict__ bias1, const float* __restrict__ bias2,
    int M, int N, int K, int lda)
{
  __shared__ __align__(16) u16 lA[2][256*64];
  __shared__ __align__(16) u16 lB[3][192*64];
  int nwg = gridDim.x;
  int bid = blockIdx.x;
  int half = 0;
  if (MODE == 2){
    int h2 = nwg >> 1;
    half = (bid >= h2) ? 1 : 0;
    bid -= half ? h2 : 0;
    nwg = h2;
  }
  int koff = half * K;
  int q = nwg >> 3;
  int swz = (bid & 7) * q + (bid >> 3);   // XCD swizzle (nwg % 8 == 0)
  int nbn = N / 192;
  int grp = nbn << 3;                     // L2 cohort: 8 bm x nbn
  int gid = swz / grp, rem = swz % grp;
  int bm = (gid << 3) + (rem & 7), bn = rem >> 3;
  int tid = threadIdx.x, lane = tid & 63;
  int wv = tid >> 6;
  int wm = wv & 1, wn = wv >> 1;          // wave tile: rows wm*128, cols wn*48
  int l15 = lane & 15, lhi = lane >> 4;
  const u16* Ag = A + (size_t)(bm << 8) * lda + koff;
  const u16* Bg = B + (size_t)(bn * 192) * lda + koff;

  // staging tables: source col slot XORed with row&7; LDS dest linear
  int srA[4], slA[4];
  #pragma unroll
  for (int i = 0; i < 4; ++i){
    int c = i*512 + tid;                  // A: 2048 chunks of 16B
    srA[i] = c >> 3;
    slA[i] = (((c & 7) ^ (srA[i] & 7)) << 3);
  }
  int srB[3], slB[3];
  #pragma unroll
  for (int i = 0; i < 3; ++i){
    int c = i*512 + tid;                  // B: 1536 chunks
    srB[i] = c >> 3;
    slB[i] = (((c & 7) ^ (srB[i] & 7)) << 3);
  }
  // swizzled read offsets (u16); 16-row sub-tile at +1024*idx
  int axr = l15 & 7;
  int aoff0 = (wm*128 + l15)*64 + ((lhi    ) ^ axr)*8;
  int aoff1 = (wm*128 + l15)*64 + ((lhi + 4) ^ axr)*8;
  int boff0 = (wn*48  + l15)*64 + ((lhi    ) ^ axr)*8;
  int boff1 = (wn*48  + l15)*64 + ((lhi + 4) ^ axr)*8;

  f32x4 acc[8][3];
  #pragma unroll
  for (int i = 0; i < 8; ++i)
    #pragma unroll
    for (int j = 0; j < 3; ++j)
      acc[i][j] = (f32x4){0.f,0.f,0.f,0.f};

  int NT = K >> 6;

#define STAGE_A(TT)                                                            \
  { int ko = (TT) << 6; u16* dA = lA[(TT) & 1];                                \
    _Pragma("unroll")                                                          \
    for (int i = 0; i < 4; ++i)                                                \
      gld_lds16(Ag + (size_t)srA[i]*lda + ko + slA[i], &dA[(i*512+tid)*8]); }
#define STAGE_B(TT)                                                            \
  { int ko = (TT) << 6; u16* dB = lB[(TT) % 3];                                \
    _Pragma("unroll")                                                          \
    for (int i = 0; i < 3; ++i)                                                \
      gld_lds16(Bg + (size_t)srB[i]*lda + ko + slB[i], &dB[(i*512+tid)*8]); }

  // prologue: A(0), B(0), B(1); wait A0+B0 (B1 stays outstanding)
  STAGE_A(0)
  STAGE_B(0)
  STAGE_B(1)
  asm volatile("s_waitcnt vmcnt(3)" ::: "memory");
  __builtin_amdgcn_s_barrier();

  for (int t = 0; t < NT; ++t){
    const u16* sA = lA[t & 1];
    const u16* sB = lB[t % 3];
    short8 bf[3][2];
    #pragma unroll
    for (int p = 0; p < 4; ++p){
      if (p == 0){
        #pragma unroll
        for (int ni = 0; ni < 3; ++ni){
          bf[ni][0] = *(const short8*)&sB[boff0 + ni*1024];
          bf[ni][1] = *(const short8*)&sB[boff1 + ni*1024];
        }
      }
      short8 a00 = *(const short8*)&sA[aoff0 + (2*p)*1024];
      short8 a01 = *(const short8*)&sA[aoff1 + (2*p)*1024];
      short8 a10 = *(const short8*)&sA[aoff0 + (2*p+1)*1024];
      short8 a11 = *(const short8*)&sA[aoff1 + (2*p+1)*1024];
      if (p == 0 && t + 1 < NT){ STAGE_A(t+1) }
      if (p == 1 && t + 2 < NT){ STAGE_B(t+2) }
      __builtin_amdgcn_s_barrier();
      asm volatile("s_waitcnt lgkmcnt(0)" ::: "memory");
      __builtin_amdgcn_sched_barrier(0);
      __builtin_amdgcn_s_setprio(1);
      #pragma unroll
      for (int ni = 0; ni < 3; ++ni){
        acc[2*p  ][ni] = mfma16(a00, bf[ni][0], acc[2*p  ][ni]);
        acc[2*p  ][ni] = mfma16(a01, bf[ni][1], acc[2*p  ][ni]);
        acc[2*p+1][ni] = mfma16(a10, bf[ni][0], acc[2*p+1][ni]);
        acc[2*p+1][ni] = mfma16(a11, bf[ni][1], acc[2*p+1][ni]);
      }
      __builtin_amdgcn_s_setprio(0);
      if (p == 3){
        if (t + 2 < NT){
          asm volatile("s_waitcnt vmcnt(3)" ::: "memory");   // A(t+1)+B(t+1) landed
        } else if (t + 1 < NT){
          asm volatile("s_waitcnt vmcnt(0)" ::: "memory");   // tail
        }
      }
      __builtin_amdgcn_s_barrier();
    }
  }
#undef STAGE_A
#undef STAGE_B

  // epilogue
  #pragma unroll
  for (int ni = 0; ni < 3; ++ni){
    int n = bn*192 + wn*48 + ni*16 + l15;
    float bs;
    if (MODE == 0){
      int d = n >> 9, r = n & 511;
      int src = d*512 + (r & 3)*128 + (r >> 2);
      bs = bias1[src] + bias2[src];
    } else {
      bs = bias1[n];
    }
    #pragma unroll
    for (int mi = 0; mi < 8; ++mi){
      #pragma unroll
      for (int r = 0; r < 4; ++r){
        int m = (bm << 8) + wm*128 + mi*16 + lhi*4 + r;
        float v = acc[mi][ni][r];
        if (MODE == 2){
          if (!half) v += bs;
          ((float*)(half ? C2 : C))[(size_t)m * N + n] = v;
        } else {
          v += bs;
          if (MODE == 1)
            v = 0.5f * v * (1.0f + erff(v * 0.70710678118f));
          ((u16*)C)[(size_t)m * N + n] = f2bf(v);
        }
      }
    }
  }
}

// ---------------- LSTM scan: 48 WGs (dir x 4 batch-groups), 512 threads ----------------
// R7 structure (proven 233us); z_x now one ushort4 load per step (gate-interleaved xp).
__global__ __launch_bounds__(512) void k_scan(const u16* __restrict__ whh, const u16* __restrict__ xp,
                       u16* __restrict__ cat)
{
  __shared__ __align__(16) u16 hb[2][4*144];   // h[batch][dim], rows padded to 144 u16
  int bid = blockIdx.x;
  int d = bid >> 2, bg = bid & 3;
  int tid = threadIdx.x, lane = tid & 63, w = tid >> 6;
  int l15 = lane & 15, lhi = lane >> 4;

  u16* hbf = (u16*)hb;
  for (int i = tid; i < 2*4*144; i += 512) hbf[i] = 0;

  short8 wf[4][4];
  #pragma unroll
  for (int g = 0; g < 4; ++g)
    #pragma unroll
    for (int kk = 0; kk < 4; ++kk)
      wf[g][kk] = *(const short8*)(whh + ((size_t)d*512 + g*128 + w*16 + l15)*128 + kk*32 + lhi*8);

  int b = bg*4 + lhi;
  int dim = w*16 + l15;
  bool fwd = (d < 6);
  const u16* zbase = xp + (size_t)b*512*6144 + d*512 + dim*4;  // + s*6144

  ushort4 Z[4];
  #pragma unroll
  for (int j = 0; j < 4; ++j){
    int s = fwd ? j : 511 - j;
    Z[j] = *(const ushort4*)(zbase + (size_t)s*6144);
  }

  f32x4 a0={0.f,0.f,0.f,0.f}, a1=a0, a2=a0, a3=a0;
  float cr = 0.f;
  int head = fwd ? d : d - 6;
  int posoff = fwd ? 0 : 128;
  size_t catlane = (size_t)b*512*1536 + head*256 + posoff + dim;
  int catoff = fwd ? 0 : 511*1536;
  int catstep = fwd ? 1536 : -1536;

  int hrd = (l15 >> 2)*144 + lhi*8;
  int hwr = lhi*144 + dim;

  __syncthreads();

#define SCAN_STEP(T, RB, WB, S)                                                \
  {                                                                            \
    short8 hf0 = *(const short8*)&hb[RB][hrd + 0*32];                          \
    short8 hf1 = *(const short8*)&hb[RB][hrd + 1*32];                          \
    short8 hf2 = *(const short8*)&hb[RB][hrd + 2*32];                          \
    short8 hf3 = *(const short8*)&hb[RB][hrd + 3*32];                          \
    a0[0] = bf2f32((u32)Z[S].x); a1[0] = bf2f32((u32)Z[S].y);                  \
    a2[0] = bf2f32((u32)Z[S].z); a3[0] = bf2f32((u32)Z[S].w);                  \
    int t4 = (T) + 4; if (t4 > 511) t4 = 511;                                  \
    int s4 = fwd ? t4 : 511 - t4;                                              \
    Z[S] = *(const ushort4*)(zbase + (size_t)s4*6144);                         \
    a2 = mfma16(hf0, wf[2][0], a2); a0 = mfma16(hf0, wf[0][0], a0);            \
    a1 = mfma16(hf0, wf[1][0], a1); a3 = mfma16(hf0, wf[3][0], a3);            \
    a2 = mfma16(hf1, wf[2][1], a2); a0 = mfma16(hf1, wf[0][1], a0);            \
    a1 = mfma16(hf1, wf[1][1], a1); a3 = mfma16(hf1, wf[3][1], a3);            \
    a2 = mfma16(hf2, wf[2][2], a2); a0 = mfma16(hf2, wf[0][2], a0);            \
    a1 = mfma16(hf2, wf[1][2], a1); a3 = mfma16(hf2, wf[3][2], a3);            \
    a2 = mfma16(hf3, wf[2][3], a2); a0 = mfma16(hf3, wf[0][3], a0);            \
    a1 = mfma16(hf3, wf[1][3], a1); a3 = mfma16(hf3, wf[3][3], a3);            \
    float tg = tanhf_(a2[0]);                                                  \
    float fi = sigf(a0[0]), ff = sigf(a1[0]), fo = sigf(a3[0]);                \
    cr = ff*cr + fi*tg;                                                        \
    float hv = fo * tanhf_(cr);                                                \
    u32 hp32;                                                                  \
    asm("v_cvt_pk_bf16_f32 %0, %1, %2" : "=v"(hp32) : "v"(hv), "v"(hv));       \
    u16 hp = (u16)hp32;                                                        \
    hb[WB][hwr] = hp;                                                          \
    asm volatile("s_waitcnt lgkmcnt(0)" ::: "memory");                         \
    __builtin_amdgcn_s_barrier();                                              \
    cat[catlane + catoff] = hp;                                                \
    catoff += catstep;                                                         \
  }

  for (int t = 0; t < 512; t += 4){
    SCAN_STEP(t,   0, 1, 0)
    SCAN_STEP(t+1, 1, 0, 1)
    SCAN_STEP(t+2, 0, 1, 2)
    SCAN_STEP(t+3, 1, 0, 3)
  }
#undef SCAN_STEP
}

// ---------------- residual + LayerNorm (sums two split-K partials) ----------------
__global__ __launch_bounds__(256) void k_ln(const float* __restrict__ emb, const float* __restrict__ p0,
                     const float* __restrict__ p1,
                     const float* __restrict__ gamma, const float* __restrict__ beta,
                     float* __restrict__ out)
{
  int row = blockIdx.x, tid = threadIdx.x;
  const float* pe = emb + (size_t)row * 768;
  const float* pa = p0 + (size_t)row * 768;
  const float* pb = p1 + (size_t)row * 768;
  float v0 = pe[tid]     + pa[tid]     + pb[tid];
  float v1 = pe[tid+256] + pa[tid+256] + pb[tid+256];
  float v2 = pe[tid+512] + pa[tid+512] + pb[tid+512];
  float s = v0+v1+v2, s2 = v0*v0+v1*v1+v2*v2;
  #pragma unroll
  for (int o = 32; o > 0; o >>= 1){ s += __shfl_down(s, o); s2 += __shfl_down(s2, o); }
  __shared__ float rs[4], rq[4];
  int wv = tid >> 6;
  if ((tid & 63) == 0){ rs[wv] = s; rq[wv] = s2; }
  __syncthreads();
  s = rs[0]+rs[1]+rs[2]+rs[3];
  s2 = rq[0]+rq[1]+rq[2]+rq[3];
  float mu = s * (1.0f/768.0f);
  float var = s2 * (1.0f/768.0f) - mu*mu;
  float rr = rsqrtf(var + 1e-5f);
  float* po = out + (size_t)row * 768;
  po[tid]     = (v0-mu)*rr*gamma[tid]     + beta[tid];
  po[tid+256] = (v1-mu)*rr*gamma[tid+256] + beta[tid+256];
  po[tid+512] = (v2-mu)*rr*gamma[tid+512] + beta[tid+512];
}

extern "C" void kernel_launch(void* const* d_in, const int* in_sizes, int n_in,
                              void* d_out, int out_size, void* d_ws, size_t ws_size,
                              hipStream_t stream)
{
  const float* emb   = (const float*)d_in[0];
  const float* W_ih  = (const float*)d_in[1];
  const float* W_hh  = (const float*)d_in[2];
  const float* b_ih  = (const float*)d_in[3];
  const float* b_hh  = (const float*)d_in[4];
  const float* W_int = (const float*)d_in[5];
  const float* b_int = (const float*)d_in[6];
  const float* W_out = (const float*)d_in[7];
  const float* b_out = (const float*)d_in[8];
  const float* gamma = (const float*)d_in[9];
  const float* beta  = (const float*)d_in[10];
  float* out = (float*)d_out;

  char* ws = (char*)d_ws;
  u16* embb  = (u16*)(ws + 0);           // 12,582,912
  u16* wihb  = (u16*)(ws + 12582912);    //  9,437,184 (permuted rows)
  u16* whhb  = (u16*)(ws + 22020096);    //  1,572,864
  u16* wintb = (u16*)(ws + 23592960);    //  9,437,184
  u16* woutb = (u16*)(ws + 33030144);    //  4,718,592
  u16* catb  = (u16*)(ws + 37748736);    // 25,165,824 (dead after GEMM1)
  float* proj1=(float*)(ws + 37748736);  // 25,165,824 (overlays catb)
  u16* xp    = (u16*)(ws + 62914560);    // 100,663,296 (dead after scan)
  u16* interb= (u16*)(ws + 62914560);    // 50,331,648 (reuses xp)
  float* proj0=(float*)(ws + 113246208); // 25,165,824 (reuses xp tail)

  // casts: emb, W_hh, W_int, W_out (flat) + W_ih (permuted)
  hipLaunchKernelGGL(k_castall, dim3(13824), dim3(256), 0, stream,
                     emb, W_hh, W_int, W_out, embb, whhb, wintb, woutb);
  hipLaunchKernelGGL(k_permw, dim3(6144), dim3(192), 0, stream, W_ih, wihb);

  // x-projection: [8192,768] x [6144,768]^T -> xp row-major (gate-interleaved cols)
  hipLaunchKernelGGL((k_gemm3<0>), dim3(1024), dim3(512), 0, stream,
                     embb, wihb, (void*)xp, nullptr, b_ih, b_hh, 8192, 6144, 768, 768);
  // sequential BiLSTM scan -> cat [16,512,1536] bf16
  hipLaunchKernelGGL(k_scan, dim3(48), dim3(512), 0, stream, whhb, xp, catb);
  // FFN up + gelu: [8192,1536] x [3072,1536]^T -> inter bf16
  hipLaunchKernelGGL((k_gemm3<1>), dim3(512), dim3(512), 0, stream,
                     catb, wintb, (void*)interb, nullptr, b_int, nullptr, 8192, 3072, 1536, 1536);
  // FFN down, split-K x2: [8192,3072] x [768,3072]^T -> proj0 (half0) + proj1 (half1)
  hipLaunchKernelGGL((k_gemm3<2>), dim3(256), dim3(512), 0, stream,
                     interb, woutb, (void*)proj0, (void*)proj1, b_out, nullptr, 8192, 768, 1536, 3072);
  // residual + LayerNorm
  hipLaunchKernelGGL(k_ln, dim3(8192), dim3(256), 0, stream, emb, proj0, proj1, gamma, beta, out);
}

// Round 12
// 503.345 us; speedup vs baseline: 1.2075x; 1.0055x over previous
//
#include <hip/hip_runtime.h>

typedef __attribute__((ext_vector_type(4))) float f32x4;
typedef __attribute__((ext_vector_type(8))) short short8;
typedef unsigned short u16;
typedef unsigned int u32;

__device__ __forceinline__ u16 f2bf(float f){
  u32 x = __float_as_uint(f);
  u32 r = x + 0x7fffu + ((x >> 16) & 1u);
  return (u16)(r >> 16);
}
__device__ __forceinline__ float bf2f32(u32 u){ return __uint_as_float(u << 16); }

__device__ __forceinline__ void gld_lds16(const u16* g, u16* l){
  __builtin_amdgcn_global_load_lds((const __attribute__((address_space(1))) void*)g,
                                   (__attribute__((address_space(3))) void*)l, 16, 0, 0);
}

__device__ __forceinline__ f32x4 mfma16(short8 a, short8 b, f32x4 c){
  return __builtin_amdgcn_mfma_f32_16x16x32_bf16(a, b, c, 0, 0, 0);
}

__device__ __forceinline__ float sigf(float x){
  return __builtin_amdgcn_rcpf(1.0f + __expf(-x));
}
__device__ __forceinline__ float tanhf_(float x){
  float e = __expf(2.0f * x);
  return 1.0f - 2.0f * __builtin_amdgcn_rcpf(e + 1.0f);
}

// ---------------- fused cast f32 -> bf16 (emb, W_hh, W_int, W_out) ----------------
__global__ __launch_bounds__(256) void k_castall(const float* __restrict__ s0, const float* __restrict__ s1,
                          const float* __restrict__ s2, const float* __restrict__ s3,
                          u16* __restrict__ d0, u16* __restrict__ d1, u16* __restrict__ d2,
                          u16* __restrict__ d3)
{
  int i = blockIdx.x * 256 + threadIdx.x;   // float4 index, total 3538944
  const float* s; u16* d; int off;
  if (i < 1572864)      { s = s0; d = d0; off = i; }
  else if (i < 1769472) { s = s1; d = d1; off = i - 1572864; }
  else if (i < 2949120) { s = s2; d = d2; off = i - 1769472; }
  else                  { s = s3; d = d3; off = i - 2949120; }
  float4 v = ((const float4*)s)[off];
  ushort4 o; o.x=f2bf(v.x); o.y=f2bf(v.y); o.z=f2bf(v.z); o.w=f2bf(v.w);
  ((ushort4*)d)[off] = o;
}

// ---------------- W_ih permute-cast: dest row n' = d*512 + dim*4 + gate ----------------
__global__ __launch_bounds__(192) void k_permw(const float* __restrict__ wih, u16* __restrict__ dst)
{
  int np = blockIdx.x;            // dest row 0..6143
  int d = np >> 9, r = np & 511;
  int src = d*512 + (r & 3)*128 + (r >> 2);
  float4 v = ((const float4*)(wih + (size_t)src*768))[threadIdx.x];
  ushort4 o; o.x=f2bf(v.x); o.y=f2bf(v.y); o.z=f2bf(v.z); o.w=f2bf(v.w);
  ((ushort4*)(dst + (size_t)np*768))[threadIdx.x] = o;
}

// -------- unified pipelined GEMM: BM=256, BN=192, BK=64 (A[M,K] rm, B[N,K] rm) --------
// 8 waves (2M x 4N), wave tile 128x48. LDS 136KB: A 2-buf (64KB) + B 3-buf (72KB).
// 4-phase skeleton per K-tile; p0 issues A(t+1), p1 issues B(t+2); p3 waits COUNTED
// vmcnt(3) (A(t+1)+B(t+1) landed, B(t+2) in flight). NO lgkmcnt/sched_barrier pin:
// ds_reads are plain C++ loads -> compiler emits fine-grained counted lgkmcnt (m97/m141).
// XOR swizzle both-sides. MODE 0: +b_ih+b_hh perm-gathered, bf16. MODE 1: +bias gelu
// bf16. MODE 2: split-K grid halves, f32 to C/C2.
template<int MODE>
__global__ __launch_bounds__(512) void k_gemm3(
    const u16* __restrict__ A, const u16* __restrict__ B,
    void* __restrict__ C, void* __restrict__ C2,
    const float* __restrict__ bias1, const float* __restrict__ bias2,
    int M, int N, int K, int lda)
{
  __shared__ __align__(16) u16 lA[2][256*64];
  __shared__ __align__(16) u16 lB[3][192*64];
  int nwg = gridDim.x;
  int bid = blockIdx.x;
  int half = 0;
  if (MODE == 2){
    int h2 = nwg >> 1;
    half = (bid >= h2) ? 1 : 0;
    bid -= half ? h2 : 0;
    nwg = h2;
  }
  int koff = half * K;
  int q = nwg >> 3;
  int swz = (bid & 7) * q + (bid >> 3);   // XCD swizzle (nwg % 8 == 0)
  int nbn = N / 192;
  int grp = nbn << 3;                     // L2 cohort: 8 bm x nbn
  int gid = swz / grp, rem = swz % grp;
  int bm = (gid << 3) + (rem & 7), bn = rem >> 3;
  int tid = threadIdx.x, lane = tid & 63;
  int wv = tid >> 6;
  int wm = wv & 1, wn = wv >> 1;          // wave tile: rows wm*128, cols wn*48
  int l15 = lane & 15, lhi = lane >> 4;
  const u16* Ag = A + (size_t)(bm << 8) * lda + koff;
  const u16* Bg = B + (size_t)(bn * 192) * lda + koff;

  int srA[4], slA[4];
  #pragma unroll
  for (int i = 0; i < 4; ++i){
    int c = i*512 + tid;                  // A: 2048 chunks of 16B
    srA[i] = c >> 3;
    slA[i] = (((c & 7) ^ (srA[i] & 7)) << 3);
  }
  int srB[3], slB[3];
  #pragma unroll
  for (int i = 0; i < 3; ++i){
    int c = i*512 + tid;                  // B: 1536 chunks
    srB[i] = c >> 3;
    slB[i] = (((c & 7) ^ (srB[i] & 7)) << 3);
  }
  int axr = l15 & 7;
  int aoff0 = (wm*128 + l15)*64 + ((lhi    ) ^ axr)*8;
  int aoff1 = (wm*128 + l15)*64 + ((lhi + 4) ^ axr)*8;
  int boff0 = (wn*48  + l15)*64 + ((lhi    ) ^ axr)*8;
  int boff1 = (wn*48  + l15)*64 + ((lhi + 4) ^ axr)*8;

  f32x4 acc[8][3];
  #pragma unroll
  for (int i = 0; i < 8; ++i)
    #pragma unroll
    for (int j = 0; j < 3; ++j)
      acc[i][j] = (f32x4){0.f,0.f,0.f,0.f};

  int NT = K >> 6;

#define STAGE_A(TT)                                                            \
  { int ko = (TT) << 6; u16* dA = lA[(TT) & 1];                                \
    _Pragma("unroll")                                                          \
    for (int i = 0; i < 4; ++i)                                                \
      gld_lds16(Ag + (size_t)srA[i]*lda + ko + slA[i], &dA[(i*512+tid)*8]); }
#define STAGE_B(TT)                                                            \
  { int ko = (TT) << 6; u16* dB = lB[(TT) % 3];                                \
    _Pragma("unroll")                                                          \
    for (int i = 0; i < 3; ++i)                                                \
      gld_lds16(Bg + (size_t)srB[i]*lda + ko + slB[i], &dB[(i*512+tid)*8]); }

  STAGE_A(0)
  STAGE_B(0)
  STAGE_B(1)
  asm volatile("s_waitcnt vmcnt(3)" ::: "memory");
  __builtin_amdgcn_s_barrier();

  for (int t = 0; t < NT; ++t){
    const u16* sA = lA[t & 1];
    const u16* sB = lB[t % 3];
    short8 bf[3][2];
    #pragma unroll
    for (int p = 0; p < 4; ++p){
      if (p == 0){
        #pragma unroll
        for (int ni = 0; ni < 3; ++ni){
          bf[ni][0] = *(const short8*)&sB[boff0 + ni*1024];
          bf[ni][1] = *(const short8*)&sB[boff1 + ni*1024];
        }
      }
      short8 a00 = *(const short8*)&sA[aoff0 + (2*p)*1024];
      short8 a01 = *(const short8*)&sA[aoff1 + (2*p)*1024];
      short8 a10 = *(const short8*)&sA[aoff0 + (2*p+1)*1024];
      short8 a11 = *(const short8*)&sA[aoff1 + (2*p+1)*1024];
      if (p == 0 && t + 1 < NT){ STAGE_A(t+1) }
      if (p == 1 && t + 2 < NT){ STAGE_B(t+2) }
      asm volatile("s_barrier" ::: "memory");
      __builtin_amdgcn_s_setprio(1);
      #pragma unroll
      for (int ni = 0; ni < 3; ++ni){
        acc[2*p  ][ni] = mfma16(a00, bf[ni][0], acc[2*p  ][ni]);
        acc[2*p  ][ni] = mfma16(a01, bf[ni][1], acc[2*p  ][ni]);
        acc[2*p+1][ni] = mfma16(a10, bf[ni][0], acc[2*p+1][ni]);
        acc[2*p+1][ni] = mfma16(a11, bf[ni][1], acc[2*p+1][ni]);
      }
      __builtin_amdgcn_s_setprio(0);
      if (p == 3){
        if (t + 2 < NT){
          asm volatile("s_waitcnt vmcnt(3)" ::: "memory");
        } else if (t + 1 < NT){
          asm volatile("s_waitcnt vmcnt(0)" ::: "memory");
        }
      }
      asm volatile("s_barrier" ::: "memory");
    }
  }
#undef STAGE_A
#undef STAGE_B

  // epilogue
  #pragma unroll
  for (int ni = 0; ni < 3; ++ni){
    int n = bn*192 + wn*48 + ni*16 + l15;
    float bs;
    if (MODE == 0){
      int d = n >> 9, r = n & 511;
      int src = d*512 + (r & 3)*128 + (r >> 2);
      bs = bias1[src] + bias2[src];
    } else {
      bs = bias1[n];
    }
    #pragma unroll
    for (int mi = 0; mi < 8; ++mi){
      #pragma unroll
      for (int r = 0; r < 4; ++r){
        int m = (bm << 8) + wm*128 + mi*16 + lhi*4 + r;
        float v = acc[mi][ni][r];
        if (MODE == 2){
          if (!half) v += bs;
          ((float*)(half ? C2 : C))[(size_t)m * N + n] = v;
        } else {
          v += bs;
          if (MODE == 1)
            v = 0.5f * v * (1.0f + erff(v * 0.70710678118f));
          ((u16*)C)[(size_t)m * N + n] = f2bf(v);
        }
      }
    }
  }
}

// ---------------- LSTM scan: 48 WGs (dir x 4 batch-groups), 512 threads ----------------
__global__ __launch_bounds__(512) void k_scan(const u16* __restrict__ whh, const u16* __restrict__ xp,
                       u16* __restrict__ cat)
{
  __shared__ __align__(16) u16 hb[2][4*144];   // h[batch][dim], rows padded to 144 u16
  int bid = blockIdx.x;
  int d = bid >> 2, bg = bid & 3;
  int tid = threadIdx.x, lane = tid & 63, w = tid >> 6;
  int l15 = lane & 15, lhi = lane >> 4;

  u16* hbf = (u16*)hb;
  for (int i = tid; i < 2*4*144; i += 512) hbf[i] = 0;

  short8 wf[4][4];
  #pragma unroll
  for (int g = 0; g < 4; ++g)
    #pragma unroll
    for (int kk = 0; kk < 4; ++kk)
      wf[g][kk] = *(const short8*)(whh + ((size_t)d*512 + g*128 + w*16 + l15)*128 + kk*32 + lhi*8);

  int b = bg*4 + lhi;
  int dim = w*16 + l15;
  bool fwd = (d < 6);
  const u16* zbase = xp + (size_t)b*512*6144 + d*512 + dim*4;  // + s*6144

  ushort4 Z[4];
  #pragma unroll
  for (int j = 0; j < 4; ++j){
    int s = fwd ? j : 511 - j;
    Z[j] = *(const ushort4*)(zbase + (size_t)s*6144);
  }

  f32x4 a0={0.f,0.f,0.f,0.f}, a1=a0, a2=a0, a3=a0;
  float cr = 0.f;
  int head = fwd ? d : d - 6;
  int posoff = fwd ? 0 : 128;
  size_t catlane = (size_t)b*512*1536 + head*256 + posoff + dim;
  int catoff = fwd ? 0 : 511*1536;
  int catstep = fwd ? 1536 : -1536;

  int hrd = (l15 >> 2)*144 + lhi*8;
  int hwr = lhi*144 + dim;

  __syncthreads();

#define SCAN_STEP(T, RB, WB, S)                                                \
  {                                                                            \
    short8 hf0 = *(const short8*)&hb[RB][hrd + 0*32];                          \
    short8 hf1 = *(const short8*)&hb[RB][hrd + 1*32];                          \
    short8 hf2 = *(const short8*)&hb[RB][hrd + 2*32];                          \
    short8 hf3 = *(const short8*)&hb[RB][hrd + 3*32];                          \
    a0[0] = bf2f32((u32)Z[S].x); a1[0] = bf2f32((u32)Z[S].y);                  \
    a2[0] = bf2f32((u32)Z[S].z); a3[0] = bf2f32((u32)Z[S].w);                  \
    int t4 = (T) + 4; if (t4 > 511) t4 = 511;                                  \
    int s4 = fwd ? t4 : 511 - t4;                                              \
    Z[S] = *(const ushort4*)(zbase + (size_t)s4*6144);                         \
    a2 = mfma16(hf0, wf[2][0], a2); a0 = mfma16(hf0, wf[0][0], a0);            \
    a1 = mfma16(hf0, wf[1][0], a1); a3 = mfma16(hf0, wf[3][0], a3);            \
    a2 = mfma16(hf1, wf[2][1], a2); a0 = mfma16(hf1, wf[0][1], a0);            \
    a1 = mfma16(hf1, wf[1][1], a1); a3 = mfma16(hf1, wf[3][1], a3);            \
    a2 = mfma16(hf2, wf[2][2], a2); a0 = mfma16(hf2, wf[0][2], a0);            \
    a1 = mfma16(hf2, wf[1][2], a1); a3 = mfma16(hf2, wf[3][2], a3);            \
    a2 = mfma16(hf3, wf[2][3], a2); a0 = mfma16(hf3, wf[0][3], a0);            \
    a1 = mfma16(hf3, wf[1][3], a1); a3 = mfma16(hf3, wf[3][3], a3);            \
    float tg = tanhf_(a2[0]);                                                  \
    float fi = sigf(a0[0]), ff = sigf(a1[0]), fo = sigf(a3[0]);                \
    cr = ff*cr + fi*tg;                                                        \
    float hv = fo * tanhf_(cr);                                                \
    u32 hp32;                                                                  \
    asm("v_cvt_pk_bf16_f32 %0, %1, %2" : "=v"(hp32) : "v"(hv), "v"(hv));       \
    u16 hp = (u16)hp32;                                                        \
    hb[WB][hwr] = hp;                                                          \
    cat[catlane + catoff] = hp;                                                \
    catoff += catstep;                                                         \
    asm volatile("s_waitcnt lgkmcnt(0)" ::: "memory");                         \
    __builtin_amdgcn_s_barrier();                                              \
  }

  for (int t = 0; t < 512; t += 4){
    SCAN_STEP(t,   0, 1, 0)
    SCAN_STEP(t+1, 1, 0, 1)
    SCAN_STEP(t+2, 0, 1, 2)
    SCAN_STEP(t+3, 1, 0, 3)
  }
#undef SCAN_STEP
}

// ---------------- residual + LayerNorm (sums two split-K partials) ----------------
__global__ __launch_bounds__(256) void k_ln(const float* __restrict__ emb, const float* __restrict__ p0,
                     const float* __restrict__ p1,
                     const float* __restrict__ gamma, const float* __restrict__ beta,
                     float* __restrict__ out)
{
  int row = blockIdx.x, tid = threadIdx.x;
  const float* pe = emb + (size_t)row * 768;
  const float* pa = p0 + (size_t)row * 768;
  const float* pb = p1 + (size_t)row * 768;
  float v0 = pe[tid]     + pa[tid]     + pb[tid];
  float v1 = pe[tid+256] + pa[tid+256] + pb[tid+256];
  float v2 = pe[tid+512] + pa[tid+512] + pb[tid+512];
  float s = v0+v1+v2, s2 = v0*v0+v1*v1+v2*v2;
  #pragma unroll
  for (int o = 32; o > 0; o >>= 1){ s += __shfl_down(s, o); s2 += __shfl_down(s2, o); }
  __shared__ float rs[4], rq[4];
  int wv = tid >> 6;
  if ((tid & 63) == 0){ rs[wv] = s; rq[wv] = s2; }
  __syncthreads();
  s = rs[0]+rs[1]+rs[2]+rs[3];
  s2 = rq[0]+rq[1]+rq[2]+rq[3];
  float mu = s * (1.0f/768.0f);
  float var = s2 * (1.0f/768.0f) - mu*mu;
  float rr = rsqrtf(var + 1e-5f);
  float* po = out + (size_t)row * 768;
  po[tid]     = (v0-mu)*rr*gamma[tid]     + beta[tid];
  po[tid+256] = (v1-mu)*rr*gamma[tid+256] + beta[tid+256];
  po[tid+512] = (v2-mu)*rr*gamma[tid+512] + beta[tid+512];
}

extern "C" void kernel_launch(void* const* d_in, const int* in_sizes, int n_in,
                              void* d_out, int out_size, void* d_ws, size_t ws_size,
                              hipStream_t stream)
{
  const float* emb   = (const float*)d_in[0];
  const float* W_ih  = (const float*)d_in[1];
  const float* W_hh  = (const float*)d_in[2];
  const float* b_ih  = (const float*)d_in[3];
  const float* b_hh  = (const float*)d_in[4];
  const float* W_int = (const float*)d_in[5];
  const float* b_int = (const float*)d_in[6];
  const float* W_out = (const float*)d_in[7];
  const float* b_out = (const float*)d_in[8];
  const float* gamma = (const float*)d_in[9];
  const float* beta  = (const float*)d_in[10];
  float* out = (float*)d_out;

  char* ws = (char*)d_ws;
  u16* embb  = (u16*)(ws + 0);           // 12,582,912
  u16* wihb  = (u16*)(ws + 12582912);    //  9,437,184 (permuted rows)
  u16* whhb  = (u16*)(ws + 22020096);    //  1,572,864
  u16* wintb = (u16*)(ws + 23592960);    //  9,437,184
  u16* woutb = (u16*)(ws + 33030144);    //  4,718,592
  u16* catb  = (u16*)(ws + 37748736);    // 25,165,824 (dead after GEMM1)
  float* proj1=(float*)(ws + 37748736);  // 25,165,824 (overlays catb)
  u16* xp    = (u16*)(ws + 62914560);    // 100,663,296 (dead after scan)
  u16* interb= (u16*)(ws + 62914560);    // 50,331,648 (reuses xp)
  float* proj0=(float*)(ws + 113246208); // 25,165,824 (reuses xp tail)

  hipLaunchKernelGGL(k_castall, dim3(13824), dim3(256), 0, stream,
                     emb, W_hh, W_int, W_out, embb, whhb, wintb, woutb);
  hipLaunchKernelGGL(k_permw, dim3(6144), dim3(192), 0, stream, W_ih, wihb);

  // x-projection: [8192,768] x [6144,768]^T -> xp row-major (gate-interleaved cols)
  hipLaunchKernelGGL((k_gemm3<0>), dim3(1024), dim3(512), 0, stream,
                     embb, wihb, (void*)xp, nullptr, b_ih, b_hh, 8192, 6144, 768, 768);
  // sequential BiLSTM scan -> cat [16,512,1536] bf16
  hipLaunchKernelGGL(k_scan, dim3(48), dim3(512), 0, stream, whhb, xp, catb);
  // FFN up + gelu: [8192,1536] x [3072,1536]^T -> inter bf16
  hipLaunchKernelGGL((k_gemm3<1>), dim3(512), dim3(512), 0, stream,
                     catb, wintb, (void*)interb, nullptr, b_int, nullptr, 8192, 3072, 1536, 1536);
  // FFN down, split-K x2: [8192,3072] x [768,3072]^T -> proj0 (half0) + proj1 (half1)
  hipLaunchKernelGGL((k_gemm3<2>), dim3(256), dim3(512), 0, stream,
                     interb, woutb, (void*)proj0, (void*)proj1, b_out, nullptr, 8192, 768, 1536, 3072);
  // residual + LayerNorm
  hipLaunchKernelGGL(k_ln, dim3(8192), dim3(256), 0, stream, emb, proj0, proj1, gamma, beta, out);
}

// Round 13
// 499.335 us; speedup vs baseline: 1.2172x; 1.0080x over previous
//
#include <hip/hip_runtime.h>

typedef __attribute__((ext_vector_type(4))) float f32x4;
typedef __attribute__((ext_vector_type(8))) short short8;
typedef unsigned short u16;
typedef unsigned int u32;

__device__ __forceinline__ u16 f2bf(float f){
  u32 x = __float_as_uint(f);
  u32 r = x + 0x7fffu + ((x >> 16) & 1u);
  return (u16)(r >> 16);
}
__device__ __forceinline__ float bf2f32(u32 u){ return __uint_as_float(u << 16); }

__device__ __forceinline__ void gld_lds16(const u16* g, u16* l){
  __builtin_amdgcn_global_load_lds((const __attribute__((address_space(1))) void*)g,
                                   (__attribute__((address_space(3))) void*)l, 16, 0, 0);
}

__device__ __forceinline__ f32x4 mfma16(short8 a, short8 b, f32x4 c){
  return __builtin_amdgcn_mfma_f32_16x16x32_bf16(a, b, c, 0, 0, 0);
}

__device__ __forceinline__ float sigf(float x){
  return __builtin_amdgcn_rcpf(1.0f + __expf(-x));
}
__device__ __forceinline__ float tanhf_(float x){
  float e = __expf(2.0f * x);
  return 1.0f - 2.0f * __builtin_amdgcn_rcpf(e + 1.0f);
}

// ---------------- fused cast f32 -> bf16 (emb, W_hh, W_int, W_out) ----------------
__global__ __launch_bounds__(256) void k_castall(const float* __restrict__ s0, const float* __restrict__ s1,
                          const float* __restrict__ s2, const float* __restrict__ s3,
                          u16* __restrict__ d0, u16* __restrict__ d1, u16* __restrict__ d2,
                          u16* __restrict__ d3)
{
  int i = blockIdx.x * 256 + threadIdx.x;   // float4 index, total 3538944
  const float* s; u16* d; int off;
  if (i < 1572864)      { s = s0; d = d0; off = i; }
  else if (i < 1769472) { s = s1; d = d1; off = i - 1572864; }
  else if (i < 2949120) { s = s2; d = d2; off = i - 1769472; }
  else                  { s = s3; d = d3; off = i - 2949120; }
  float4 v = ((const float4*)s)[off];
  ushort4 o; o.x=f2bf(v.x); o.y=f2bf(v.y); o.z=f2bf(v.z); o.w=f2bf(v.w);
  ((ushort4*)d)[off] = o;
}

// ---------------- W_ih permute-cast: dest row n' = d*512 + dim*4 + gate ----------------
__global__ __launch_bounds__(192) void k_permw(const float* __restrict__ wih, u16* __restrict__ dst)
{
  int np = blockIdx.x;            // dest row 0..6143
  int d = np >> 9, r = np & 511;
  int src = d*512 + (r & 3)*128 + (r >> 2);
  float4 v = ((const float4*)(wih + (size_t)src*768))[threadIdx.x];
  ushort4 o; o.x=f2bf(v.x); o.y=f2bf(v.y); o.z=f2bf(v.z); o.w=f2bf(v.w);
  ((ushort4*)(dst + (size_t)np*768))[threadIdx.x] = o;
}

// -------- persistent pipelined GEMM: BM=256, BN=192, BK=64, TPW tiles/WG --------------
// Each WG streams TPW consecutive bn-tiles (fixed bm) as ONE K-stream: stream idx tt,
// A buf tt&1, B buf tt%3; p0 stages A(tt+1), p1 stages B(tt+2) (crossing tile bounds);
// p3 waits COUNTED vmcnt(3) - the pipeline never drains mid-stream. Tile boundary =
// acc->C epilogue after the p3 barrier; stores retire under next tile's compute.
// Grid = exactly 256 WGs (1 CU round) for all shapes. XOR swizzle both-sides.
// MODE 0: +b_ih+b_hh perm-gathered, bf16. MODE 1: +bias gelu bf16. MODE 2: split-K
// grid halves, f32 to C/C2.
template<int MODE, int TPW>
__global__ __launch_bounds__(512) void k_gemmp(
    const u16* __restrict__ A, const u16* __restrict__ B,
    void* __restrict__ C, void* __restrict__ C2,
    const float* __restrict__ bias1, const float* __restrict__ bias2,
    int M, int N, int K, int lda)
{
  __shared__ __align__(16) u16 lA[2][256*64];
  __shared__ __align__(16) u16 lB[3][192*64];
  int nwg = gridDim.x;
  int bid = blockIdx.x;
  int half = 0;
  if (MODE == 2){
    int h2 = nwg >> 1;
    half = (bid >= h2) ? 1 : 0;
    bid -= half ? h2 : 0;
    nwg = h2;
  }
  int koff = half * K;
  int q = nwg >> 3;
  int swz = (bid & 7) * q + (bid >> 3);   // XCD swizzle (nwg % 8 == 0)
  int nbng = N / (192 * TPW);
  int bm = swz / nbng, bng = swz % nbng;  // XCD chunk shares bm cohort (A in L2)
  int tid = threadIdx.x, lane = tid & 63;
  int wv = tid >> 6;
  int wm = wv & 1, wn = wv >> 1;          // wave tile: rows wm*128, cols wn*48
  int l15 = lane & 15, lhi = lane >> 4;
  const u16* Ag = A + (size_t)(bm << 8) * lda + koff;
  const u16* Bg0 = B + (size_t)(bng * TPW) * 192 * lda + koff;
  size_t bstep = (size_t)192 * lda;

  int srA[4], slA[4];
  #pragma unroll
  for (int i = 0; i < 4; ++i){
    int c = i*512 + tid;                  // A: 2048 chunks of 16B
    srA[i] = c >> 3;
    slA[i] = (((c & 7) ^ (srA[i] & 7)) << 3);
  }
  int srB[3], slB[3];
  #pragma unroll
  for (int i = 0; i < 3; ++i){
    int c = i*512 + tid;                  // B: 1536 chunks
    srB[i] = c >> 3;
    slB[i] = (((c & 7) ^ (srB[i] & 7)) << 3);
  }
  int axr = l15 & 7;
  int aoff0 = (wm*128 + l15)*64 + ((lhi    ) ^ axr)*8;
  int aoff1 = (wm*128 + l15)*64 + ((lhi + 4) ^ axr)*8;
  int boff0 = (wn*48  + l15)*64 + ((lhi    ) ^ axr)*8;
  int boff1 = (wn*48  + l15)*64 + ((lhi + 4) ^ axr)*8;

  f32x4 acc[8][3];
  #pragma unroll
  for (int i = 0; i < 8; ++i)
    #pragma unroll
    for (int j = 0; j < 3; ++j)
      acc[i][j] = (f32x4){0.f,0.f,0.f,0.f};

  int NT = K >> 6;
  int TOT = NT * TPW;

#define STAGE_A(SS)                                                            \
  { int ss_ = (SS); int ko = (ss_ % NT) << 6; u16* dA = lA[ss_ & 1];           \
    _Pragma("unroll")                                                          \
    for (int i = 0; i < 4; ++i)                                                \
      gld_lds16(Ag + (size_t)srA[i]*lda + ko + slA[i], &dA[(i*512+tid)*8]); }
#define STAGE_B(SS)                                                            \
  { int ss_ = (SS); int ko = (ss_ % NT) << 6;                                  \
    const u16* Bb = Bg0 + (size_t)(ss_ / NT) * bstep;                          \
    u16* dB = lB[ss_ % 3];                                                     \
    _Pragma("unroll")                                                          \
    for (int i = 0; i < 3; ++i)                                                \
      gld_lds16(Bb + (size_t)srB[i]*lda + ko + slB[i], &dB[(i*512+tid)*8]); }

  STAGE_A(0)
  STAGE_B(0)
  STAGE_B(1)
  asm volatile("s_waitcnt vmcnt(3)" ::: "memory");
  __builtin_amdgcn_s_barrier();

  int kt = 0, tile = 0;
  for (int tt = 0; tt < TOT; ++tt){
    const u16* sA = lA[tt & 1];
    const u16* sB = lB[tt % 3];
    short8 bf[3][2];
    #pragma unroll
    for (int p = 0; p < 4; ++p){
      if (p == 0){
        #pragma unroll
        for (int ni = 0; ni < 3; ++ni){
          bf[ni][0] = *(const short8*)&sB[boff0 + ni*1024];
          bf[ni][1] = *(const short8*)&sB[boff1 + ni*1024];
        }
      }
      short8 a00 = *(const short8*)&sA[aoff0 + (2*p)*1024];
      short8 a01 = *(const short8*)&sA[aoff1 + (2*p)*1024];
      short8 a10 = *(const short8*)&sA[aoff0 + (2*p+1)*1024];
      short8 a11 = *(const short8*)&sA[aoff1 + (2*p+1)*1024];
      if (p == 0 && tt + 1 < TOT){ STAGE_A(tt+1) }
      if (p == 1 && tt + 2 < TOT){ STAGE_B(tt+2) }
      asm volatile("s_barrier" ::: "memory");
      __builtin_amdgcn_s_setprio(1);
      #pragma unroll
      for (int ni = 0; ni < 3; ++ni){
        acc[2*p  ][ni] = mfma16(a00, bf[ni][0], acc[2*p  ][ni]);
        acc[2*p  ][ni] = mfma16(a01, bf[ni][1], acc[2*p  ][ni]);
        acc[2*p+1][ni] = mfma16(a10, bf[ni][0], acc[2*p+1][ni]);
        acc[2*p+1][ni] = mfma16(a11, bf[ni][1], acc[2*p+1][ni]);
      }
      __builtin_amdgcn_s_setprio(0);
      if (p == 3){
        if (tt + 2 < TOT){
          asm volatile("s_waitcnt vmcnt(3)" ::: "memory");   // A/B(tt+1) landed; B(tt+2) in flight
        } else if (tt + 1 < TOT){
          asm volatile("s_waitcnt vmcnt(0)" ::: "memory");   // tail
        }
      }
      asm volatile("s_barrier" ::: "memory");
    }

    if (kt == NT - 1){
      // tile epilogue: drain acc -> C, reset; stores retire under next tile's compute
      int bnbase = (bng * TPW + tile) * 192;
      #pragma unroll
      for (int ni = 0; ni < 3; ++ni){
        int n = bnbase + wn*48 + ni*16 + l15;
        float bs;
        if (MODE == 0){
          int d = n >> 9, r = n & 511;
          int src = d*512 + (r & 3)*128 + (r >> 2);
          bs = bias1[src] + bias2[src];
        } else {
          bs = bias1[n];
        }
        #pragma unroll
        for (int mi = 0; mi < 8; ++mi){
          #pragma unroll
          for (int r = 0; r < 4; ++r){
            int m = (bm << 8) + wm*128 + mi*16 + lhi*4 + r;
            float v = acc[mi][ni][r];
            if (MODE == 2){
              if (!half) v += bs;
              ((float*)(half ? C2 : C))[(size_t)m * N + n] = v;
            } else {
              v += bs;
              if (MODE == 1)
                v = 0.5f * v * (1.0f + erff(v * 0.70710678118f));
              ((u16*)C)[(size_t)m * N + n] = f2bf(v);
            }
            acc[mi][ni][r] = 0.f;
          }
        }
      }
      ++tile; kt = 0;
    } else {
      ++kt;
    }
  }
#undef STAGE_A
#undef STAGE_B
}

// ---------------- LSTM scan: 48 WGs (dir x 4 batch-groups), 512 threads ----------------
__global__ __launch_bounds__(512) void k_scan(const u16* __restrict__ whh, const u16* __restrict__ xp,
                       u16* __restrict__ cat)
{
  __shared__ __align__(16) u16 hb[2][4*144];   // h[batch][dim], rows padded to 144 u16
  int bid = blockIdx.x;
  int d = bid >> 2, bg = bid & 3;
  int tid = threadIdx.x, lane = tid & 63, w = tid >> 6;
  int l15 = lane & 15, lhi = lane >> 4;

  u16* hbf = (u16*)hb;
  for (int i = tid; i < 2*4*144; i += 512) hbf[i] = 0;

  short8 wf[4][4];
  #pragma unroll
  for (int g = 0; g < 4; ++g)
    #pragma unroll
    for (int kk = 0; kk < 4; ++kk)
      wf[g][kk] = *(const short8*)(whh + ((size_t)d*512 + g*128 + w*16 + l15)*128 + kk*32 + lhi*8);

  int b = bg*4 + lhi;
  int dim = w*16 + l15;
  bool fwd = (d < 6);
  const u16* zbase = xp + (size_t)b*512*6144 + d*512 + dim*4;  // + s*6144

  ushort4 Z[4];
  #pragma unroll
  for (int j = 0; j < 4; ++j){
    int s = fwd ? j : 511 - j;
    Z[j] = *(const ushort4*)(zbase + (size_t)s*6144);
  }

  f32x4 a0={0.f,0.f,0.f,0.f}, a1=a0, a2=a0, a3=a0;
  float cr = 0.f;
  int head = fwd ? d : d - 6;
  int posoff = fwd ? 0 : 128;
  size_t catlane = (size_t)b*512*1536 + head*256 + posoff + dim;
  int catoff = fwd ? 0 : 511*1536;
  int catstep = fwd ? 1536 : -1536;

  int hrd = (l15 >> 2)*144 + lhi*8;
  int hwr = lhi*144 + dim;

  __syncthreads();

#define SCAN_STEP(T, RB, WB, S)                                                \
  {                                                                            \
    short8 hf0 = *(const short8*)&hb[RB][hrd + 0*32];                          \
    short8 hf1 = *(const short8*)&hb[RB][hrd + 1*32];                          \
    short8 hf2 = *(const short8*)&hb[RB][hrd + 2*32];                          \
    short8 hf3 = *(const short8*)&hb[RB][hrd + 3*32];                          \
    a0[0] = bf2f32((u32)Z[S].x); a1[0] = bf2f32((u32)Z[S].y);                  \
    a2[0] = bf2f32((u32)Z[S].z); a3[0] = bf2f32((u32)Z[S].w);                  \
    int t4 = (T) + 4; if (t4 > 511) t4 = 511;                                  \
    int s4 = fwd ? t4 : 511 - t4;                                              \
    Z[S] = *(const ushort4*)(zbase + (size_t)s4*6144);                         \
    a2 = mfma16(hf0, wf[2][0], a2); a0 = mfma16(hf0, wf[0][0], a0);            \
    a1 = mfma16(hf0, wf[1][0], a1); a3 = mfma16(hf0, wf[3][0], a3);            \
    a2 = mfma16(hf1, wf[2][1], a2); a0 = mfma16(hf1, wf[0][1], a0);            \
    a1 = mfma16(hf1, wf[1][1], a1); a3 = mfma16(hf1, wf[3][1], a3);            \
    a2 = mfma16(hf2, wf[2][2], a2); a0 = mfma16(hf2, wf[0][2], a0);            \
    a1 = mfma16(hf2, wf[1][2], a1); a3 = mfma16(hf2, wf[3][2], a3);            \
    a2 = mfma16(hf3, wf[2][3], a2); a0 = mfma16(hf3, wf[0][3], a0);            \
    a1 = mfma16(hf3, wf[1][3], a1); a3 = mfma16(hf3, wf[3][3], a3);            \
    float tg = tanhf_(a2[0]);                                                  \
    float fi = sigf(a0[0]), ff = sigf(a1[0]), fo = sigf(a3[0]);                \
    cr = ff*cr + fi*tg;                                                        \
    float hv = fo * tanhf_(cr);                                                \
    u32 hp32;                                                                  \
    asm("v_cvt_pk_bf16_f32 %0, %1, %2" : "=v"(hp32) : "v"(hv), "v"(hv));       \
    u16 hp = (u16)hp32;                                                        \
    hb[WB][hwr] = hp;                                                          \
    cat[catlane + catoff] = hp;                                                \
    catoff += catstep;                                                         \
    asm volatile("s_waitcnt lgkmcnt(0)" ::: "memory");                         \
    __builtin_amdgcn_s_barrier();                                              \
  }

  for (int t = 0; t < 512; t += 4){
    SCAN_STEP(t,   0, 1, 0)
    SCAN_STEP(t+1, 1, 0, 1)
    SCAN_STEP(t+2, 0, 1, 2)
    SCAN_STEP(t+3, 1, 0, 3)
  }
#undef SCAN_STEP
}

// ---------------- residual + LayerNorm (sums two split-K partials) ----------------
__global__ __launch_bounds__(256) void k_ln(const float* __restrict__ emb, const float* __restrict__ p0,
                     const float* __restrict__ p1,
                     const float* __restrict__ gamma, const float* __restrict__ beta,
                     float* __restrict__ out)
{
  int row = blockIdx.x, tid = threadIdx.x;
  const float* pe = emb + (size_t)row * 768;
  const float* pa = p0 + (size_t)row * 768;
  const float* pb = p1 + (size_t)row * 768;
  float v0 = pe[tid]     + pa[tid]     + pb[tid];
  float v1 = pe[tid+256] + pa[tid+256] + pb[tid+256];
  float v2 = pe[tid+512] + pa[tid+512] + pb[tid+512];
  float s = v0+v1+v2, s2 = v0*v0+v1*v1+v2*v2;
  #pragma unroll
  for (int o = 32; o > 0; o >>= 1){ s += __shfl_down(s, o); s2 += __shfl_down(s2, o); }
  __shared__ float rs[4], rq[4];
  int wv = tid >> 6;
  if ((tid & 63) == 0){ rs[wv] = s; rq[wv] = s2; }
  __syncthreads();
  s = rs[0]+rs[1]+rs[2]+rs[3];
  s2 = rq[0]+rq[1]+rq[2]+rq[3];
  float mu = s * (1.0f/768.0f);
  float var = s2 * (1.0f/768.0f) - mu*mu;
  float rr = rsqrtf(var + 1e-5f);
  float* po = out + (size_t)row * 768;
  po[tid]     = (v0-mu)*rr*gamma[tid]     + beta[tid];
  po[tid+256] = (v1-mu)*rr*gamma[tid+256] + beta[tid+256];
  po[tid+512] = (v2-mu)*rr*gamma[tid+512] + beta[tid+512];
}

extern "C" void kernel_launch(void* const* d_in, const int* in_sizes, int n_in,
                              void* d_out, int out_size, void* d_ws, size_t ws_size,
                              hipStream_t stream)
{
  const float* emb   = (const float*)d_in[0];
  const float* W_ih  = (const float*)d_in[1];
  const float* W_hh  = (const float*)d_in[2];
  const float* b_ih  = (const float*)d_in[3];
  const float* b_hh  = (const float*)d_in[4];
  const float* W_int = (const float*)d_in[5];
  const float* b_int = (const float*)d_in[6];
  const float* W_out = (const float*)d_in[7];
  const float* b_out = (const float*)d_in[8];
  const float* gamma = (const float*)d_in[9];
  const float* beta  = (const float*)d_in[10];
  float* out = (float*)d_out;

  char* ws = (char*)d_ws;
  u16* embb  = (u16*)(ws + 0);           // 12,582,912
  u16* wihb  = (u16*)(ws + 12582912);    //  9,437,184 (permuted rows)
  u16* whhb  = (u16*)(ws + 22020096);    //  1,572,864
  u16* wintb = (u16*)(ws + 23592960);    //  9,437,184
  u16* woutb = (u16*)(ws + 33030144);    //  4,718,592
  u16* catb  = (u16*)(ws + 37748736);    // 25,165,824 (dead after GEMM1)
  float* proj1=(float*)(ws + 37748736);  // 25,165,824 (overlays catb)
  u16* xp    = (u16*)(ws + 62914560);    // 100,663,296 (dead after scan)
  u16* interb= (u16*)(ws + 62914560);    // 50,331,648 (reuses xp)
  float* proj0=(float*)(ws + 113246208); // 25,165,824 (reuses xp tail)

  hipLaunchKernelGGL(k_castall, dim3(13824), dim3(256), 0, stream,
                     emb, W_hh, W_int, W_out, embb, whhb, wintb, woutb);
  hipLaunchKernelGGL(k_permw, dim3(6144), dim3(192), 0, stream, W_ih, wihb);

  // x-projection: [8192,768] x [6144,768]^T -> xp row-major (gate-interleaved cols)
  hipLaunchKernelGGL((k_gemmp<0,4>), dim3(256), dim3(512), 0, stream,
                     embb, wihb, (void*)xp, nullptr, b_ih, b_hh, 8192, 6144, 768, 768);
  // sequential BiLSTM scan -> cat [16,512,1536] bf16
  hipLaunchKernelGGL(k_scan, dim3(48), dim3(512), 0, stream, whhb, xp, catb);
  // FFN up + gelu: [8192,1536] x [3072,1536]^T -> inter bf16
  hipLaunchKernelGGL((k_gemmp<1,2>), dim3(256), dim3(512), 0, stream,
                     catb, wintb, (void*)interb, nullptr, b_int, nullptr, 8192, 3072, 1536, 1536);
  // FFN down, split-K x2: [8192,3072] x [768,3072]^T -> proj0 (half0) + proj1 (half1)
  hipLaunchKernelGGL((k_gemmp<2,1>), dim3(256), dim3(512), 0, stream,
                     interb, woutb, (void*)proj0, (void*)proj1, b_out, nullptr, 8192, 768, 1536, 3072);
  // residual + LayerNorm
  hipLaunchKernelGGL(k_ln, dim3(8192), dim3(256), 0, stream, emb, proj0, proj1, gamma, beta, out);
}